// Round 11
// baseline (85.114 us; speedup 1.0000x reference)
//
#include <hip/hip_runtime.h>
#include <stdint.h>
#include <math.h>

#define N_PTS 8192
#define WPB   8
#define TPB   (WPB * 64)           // 512
#define NBLK  (N_PTS / WPB)        // 1024 blocks for main
#define GRIDC 64
#define NCELL (GRIDC * GRIDC)
#define CW    (9.0f / 64.0f)
#define CINV  (64.0f / 9.0f)

typedef __fp16 h2 __attribute__((ext_vector_type(2)));
typedef uint32_t u32;

__device__ __forceinline__ u32 pksub(u32 a, u32 b) {
  u32 d;
  asm("v_pk_add_f16 %0, %1, %2 neg_lo:[0,1] neg_hi:[0,1]" : "=v"(d) : "v"(a), "v"(b));
  return d;
}
__device__ __forceinline__ float dot2u(u32 a, u32 b, float c) {
#if __has_builtin(__builtin_amdgcn_fdot2)
  return __builtin_amdgcn_fdot2(__builtin_bit_cast(h2, a), __builtin_bit_cast(h2, b), c, false);
#else
  h2 x = __builtin_bit_cast(h2, a), y = __builtin_bit_cast(h2, b);
  return fmaf((float)x.x, (float)y.x, fmaf((float)x.y, (float)y.y, c));
#endif
}
__device__ __forceinline__ u32 cvtpk(float a, float b) {
  return __builtin_bit_cast(u32, __builtin_amdgcn_cvt_pkrtz(a, b));
}
__device__ __forceinline__ int cellc(float v) {
  int c = (int)floorf((v + 4.5f) * CINV);
  return c < 0 ? 0 : (c > GRIDC - 1 ? GRIDC - 1 : c);
}

// ---------------- threefry2x32 (JAX partitionable random_bits) ----------------
__device__ __forceinline__ uint32_t rotl32(uint32_t x, int r) {
  return (x << r) | (x >> (32 - r));
}
__device__ __forceinline__ uint32_t threefry_bits(uint32_t idx) {
  const uint32_t k0 = 0u, k1 = 42u;
  const uint32_t k2c = k0 ^ k1 ^ 0x1BD11BDAu;
  uint32_t x0 = 0u, x1 = idx;
  x0 += k0; x1 += k1;
  x0 += x1; x1 = rotl32(x1, 13); x1 ^= x0;
  x0 += x1; x1 = rotl32(x1, 15); x1 ^= x0;
  x0 += x1; x1 = rotl32(x1, 26); x1 ^= x0;
  x0 += x1; x1 = rotl32(x1,  6); x1 ^= x0;
  x0 += k1; x1 += k2c + 1u;
  x0 += x1; x1 = rotl32(x1, 17); x1 ^= x0;
  x0 += x1; x1 = rotl32(x1, 29); x1 ^= x0;
  x0 += x1; x1 = rotl32(x1, 16); x1 ^= x0;
  x0 += x1; x1 = rotl32(x1, 24); x1 ^= x0;
  x0 += k2c; x1 += k0 + 2u;
  x0 += x1; x1 = rotl32(x1, 13); x1 ^= x0;
  x0 += x1; x1 = rotl32(x1, 15); x1 ^= x0;
  x0 += x1; x1 = rotl32(x1, 26); x1 ^= x0;
  x0 += x1; x1 = rotl32(x1,  6); x1 ^= x0;
  x0 += k0; x1 += k1 + 3u;
  x0 += x1; x1 = rotl32(x1, 17); x1 ^= x0;
  x0 += x1; x1 = rotl32(x1, 29); x1 ^= x0;
  x0 += x1; x1 = rotl32(x1, 16); x1 ^= x0;
  x0 += x1; x1 = rotl32(x1, 24); x1 ^= x0;
  x0 += k1; x1 += k2c + 4u;
  x0 += x1; x1 = rotl32(x1, 13); x1 ^= x0;
  x0 += x1; x1 = rotl32(x1, 15); x1 ^= x0;
  x0 += x1; x1 = rotl32(x1, 26); x1 ^= x0;
  x0 += x1; x1 = rotl32(x1,  6); x1 ^= x0;
  x0 += k2c; x1 += k0 + 5u;
  return x0 ^ x1;
}
__device__ __forceinline__ float erfinv_xla(float x) {
  float w = -log1pf(-x * x);
  float p;
  if (w < 5.0f) {
    w -= 2.5f;
    p = 2.81022636e-08f;
    p = fmaf(p, w, 3.43273939e-07f);
    p = fmaf(p, w, -3.5233877e-06f);
    p = fmaf(p, w, -4.39150654e-06f);
    p = fmaf(p, w, 0.00021858087f);
    p = fmaf(p, w, -0.00125372503f);
    p = fmaf(p, w, -0.00417768164f);
    p = fmaf(p, w, 0.246640727f);
    p = fmaf(p, w, 1.50140941f);
  } else {
    w = sqrtf(w) - 3.0f;
    p = -0.000200214257f;
    p = fmaf(p, w, 0.000100950558f);
    p = fmaf(p, w, 0.00134934322f);
    p = fmaf(p, w, -0.00367342844f);
    p = fmaf(p, w, 0.00573950773f);
    p = fmaf(p, w, -0.0076224613f);
    p = fmaf(p, w, 0.00943887047f);
    p = fmaf(p, w, 1.00167406f);
    p = fmaf(p, w, 2.83297682f);
  }
  return p * x;
}
__device__ __forceinline__ float jax_noise(uint32_t idx) {
  uint32_t bits = threefry_bits(idx);
  float uf = __uint_as_float((bits >> 9) | 0x3F800000u) - 1.0f;
  const float lo_u = -0.99999994f;
  float u = fmaxf(lo_u, fmaf(uf, 2.0f, lo_u));
  return 1.4142135623730951f * erfinv_xla(u) * 0.01f;
}

// ======= K1: single-block build: hist + prefix + iimg + stats + place + rank =======
__global__ __launch_bounds__(1024) void build_kernel(const float* __restrict__ x,
                                                     float* __restrict__ stats,
                                                     u32* __restrict__ base,
                                                     u32* __restrict__ iimg,
                                                     u32* __restrict__ tmp_pt,
                                                     u32* __restrict__ tmp_ci,
                                                     u32* __restrict__ spt,
                                                     unsigned short* __restrict__ sidx) {
  __shared__ u32 baseL[NCELL];   // counts -> exclusive base -> cursor
  __shared__ u32 ssc[1024];
  __shared__ double sred[16][4];
  const int t = threadIdx.x;

#pragma unroll
  for (int k = 0; k < 4; ++k) baseL[t * 4 + k] = 0;
  __syncthreads();

  // histogram + per-thread point cache + f64 stat partials
  double s0 = 0, s1 = 0, q0 = 0, q1 = 0;
  int cellv[8]; u32 ptv[8];
#pragma unroll
  for (int k = 0; k < 8; ++k) {
    float2 p = ((const float2*)x)[t * 8 + k];
    int cell = cellc(p.y) * GRIDC + cellc(p.x);
    cellv[k] = cell; ptv[k] = cvtpk(p.x, p.y);
    atomicAdd(&baseL[cell], 1u);
    s0 += (double)p.x; s1 += (double)p.y;
    q0 += (double)p.x * (double)p.x; q1 += (double)p.y * (double)p.y;
  }
#pragma unroll
  for (int m = 1; m < 64; m <<= 1) {
    s0 += __shfl_xor(s0, m); s1 += __shfl_xor(s1, m);
    q0 += __shfl_xor(q0, m); q1 += __shfl_xor(q1, m);
  }
  if ((t & 63) == 0) {
    sred[t >> 6][0] = s0; sred[t >> 6][1] = s1;
    sred[t >> 6][2] = q0; sred[t >> 6][3] = q1;
  }
  __syncthreads();

  // prefix sum over 4096 cells (4 per thread)
  u32 c0 = baseL[t * 4], c1 = baseL[t * 4 + 1], c2 = baseL[t * 4 + 2], c3 = baseL[t * 4 + 3];
  u32 sum = c0 + c1 + c2 + c3;
  ssc[t] = sum;
  __syncthreads();
  for (int off = 1; off < 1024; off <<= 1) {
    u32 v = (t >= off) ? ssc[t - off] : 0u;
    __syncthreads();
    ssc[t] += v;
    __syncthreads();
  }
  u32 run = ssc[t] - sum;  // exclusive
  u32 b0 = run, b1 = run + c0, b2 = b1 + c1, b3 = b2 + c2;
  __syncthreads();  // all count reads done
  baseL[t * 4] = b0; baseL[t * 4 + 1] = b1; baseL[t * 4 + 2] = b2; baseL[t * 4 + 3] = b3;
  base[t * 4] = b0;  base[t * 4 + 1] = b1;  base[t * 4 + 2] = b2;  base[t * 4 + 3] = b3;
  if (t == 1023) base[NCELL] = N_PTS;
  if (t == 0) {  // stats finish
    double a0 = 0, a1 = 0, d0 = 0, d1 = 0;
    for (int k = 0; k < 16; ++k) {
      a0 += sred[k][0]; a1 += sred[k][1]; d0 += sred[k][2]; d1 += sred[k][3];
    }
    double n = (double)N_PTS, m0 = a0 / n, m1 = a1 / n;
    stats[0] = (float)m0; stats[1] = (float)m1;
    stats[2] = (float)sqrt((d0 - n * m0 * m0) / (n - 1.0));
    stats[3] = (float)sqrt((d1 - n * m1 * m1) / (n - 1.0));
  }
  __syncthreads();

  // integral image from pristine baseL
  if (t <= 64) {
    u32 acc = 0;
    iimg[t] = 0;
    for (int yy = 0; yy < GRIDC; ++yy) {
      int idx = yy * GRIDC + t;
      u32 v = (idx < NCELL) ? baseL[idx] : (u32)N_PTS;
      acc += v - baseL[yy * GRIDC];
      iimg[(yy + 1) * 65 + t] = acc;
    }
  }
  __syncthreads();

  // place via LDS cursor atomics (mutates baseL)
#pragma unroll
  for (int k = 0; k < 8; ++k) {
    u32 slot = atomicAdd(&baseL[cellv[k]], 1u);
    tmp_pt[slot] = ptv[k];
    tmp_ci[slot] = ((u32)cellv[k] << 13) | (u32)(t * 8 + k);
  }
  __threadfence();
  __syncthreads();

  // stable rank within cell -> deterministic sorted arrays
#pragma unroll
  for (int k = 0; k < 8; ++k) {
    int sl = t + k * 1024;
    u32 v = tmp_ci[sl];
    u32 cell = v >> 13, i = v & 8191u;
    u32 lo = base[cell], hi = base[cell + 1];
    u32 rank = 0;
    for (u32 j = lo; j < hi; ++j) rank += ((tmp_ci[j] & 8191u) < i) ? 1u : 0u;
    u32 d = lo + rank;
    spt[d] = tmp_pt[sl];
    sidx[d] = (unsigned short)i;
  }
}

// ======= K2: main — LDS-resident point set, windowed sigma + drift + noised h =======
__global__ __launch_bounds__(TPB, 4) void main_kernel(const float* __restrict__ x,
                                                      const float* __restrict__ stats,
                                                      const u32* __restrict__ base,
                                                      const u32* __restrict__ iimg,
                                                      const u32* __restrict__ spt,
                                                      const unsigned short* __restrict__ sidx,
                                                      float* __restrict__ hbuf) {
  __shared__ u32 sptL[N_PTS];  // 32 KB: whole sorted packed point set
  const int t = threadIdx.x;
  const int w = t >> 6;
  const int s = t & 63;

#pragma unroll
  for (int k = 0; k < 4; ++k)
    ((uint4*)sptL)[k * TPB + t] = ((const uint4*)spt)[k * TPB + t];
  __syncthreads();

  const int p = blockIdx.x * WPB + w;
  const int orig = (int)sidx[p];
  const float2 xg = ((const float2*)x)[orig];
  const u32 xihu = cvtpk(xg.x, xg.y);
  const int cx = cellc(xg.x), cy = cellc(xg.y);
  const float INF = 3.402823466e+38f;

  // pre-size r from integral image
  int r = 1;
  bool fullA = false;
  for (;;) {
    int cxl = max(cx - r, 0), cxh = min(cx + r, GRIDC - 1);
    int cyl = max(cy - r, 0), cyh = min(cy + r, GRIDC - 1);
    u32 cnt = iimg[(cyh + 1) * 65 + cxh + 1] - iimg[cyl * 65 + cxh + 1]
            - iimg[(cyh + 1) * 65 + cxl] + iimg[cyl * 65 + cxl];
    if (cnt >= 160u) break;
    int nr = (3 * r + 1) >> 1;
    if (nr > 11) { fullA = true; break; }
    r = nr;
  }

  // phase A: scan (banded stream-strided or full contiguous) + exact rank-32 + verify
  float d2k;
  for (;;) {
    float r0 = INF, r1 = INF, r2 = INF, r3 = INF, r4 = INF, r5 = INF;
    int cxl, cxh, cyl, cyh;
    if (fullA) { cxl = 0; cxh = GRIDC - 1; cyl = 0; cyh = GRIDC - 1; }
    else {
      cxl = max(cx - r, 0); cxh = min(cx + r, GRIDC - 1);
      cyl = max(cy - r, 0); cyh = min(cy + r, GRIDC - 1);
    }
#define INS6(d2)                      \
    r5 = fminf(fmaxf(r4, d2), r5);    \
    r4 = fminf(fmaxf(r3, d2), r4);    \
    r3 = fminf(fmaxf(r2, d2), r3);    \
    r2 = fminf(fmaxf(r1, d2), r2);    \
    r1 = fminf(fmaxf(r0, d2), r1);    \
    r0 = fminf(r0, d2);
    if (fullA) {
      for (u32 j = (u32)s; j < N_PTS; j += 64u) {
        u32 qp = sptL[j];
        u32 e = pksub(xihu, qp);
        float d2 = dot2u(e, e, 0.0f);
        INS6(d2);
      }
    } else {
      u32 acc = 0;  // continuous stream striding across bands
      for (int yy = cyl; yy <= cyh; ++yy) {
        const int rowb = yy << 6;
        u32 lo = base[rowb + cxl];
        u32 len = base[rowb + cxh + 1] - lo;
        u32 k0 = ((u32)s - acc) & 63u;
        for (u32 k = k0; k < len; k += 64u) {
          u32 qp = sptL[lo + k];
          u32 e = pksub(xihu, qp);
          float d2 = dot2u(e, e, 0.0f);
          INS6(d2);
        }
        acc += len;
      }
    }
#undef INS6
    // exact rank-32 over 64 sorted cap-6 lists (f16-bit binary search)
    u32 b0 = (u32)__builtin_bit_cast(unsigned short, (__fp16)r0);
    u32 b1 = (u32)__builtin_bit_cast(unsigned short, (__fp16)r1);
    u32 b2 = (u32)__builtin_bit_cast(unsigned short, (__fp16)r2);
    u32 b3 = (u32)__builtin_bit_cast(unsigned short, (__fp16)r3);
    u32 b4 = (u32)__builtin_bit_cast(unsigned short, (__fp16)r4);
    u32 b5 = (u32)__builtin_bit_cast(unsigned short, (__fp16)r5);
    u32 blo = 0u, bhi = 0x7C01u;
    for (int it = 0; it < 15; ++it) {
      u32 mid = (blo + bhi) >> 1;
      int c = __popcll(__ballot(b0 < mid)) + __popcll(__ballot(b1 < mid)) +
              __popcll(__ballot(b2 < mid)) + __popcll(__ballot(b3 < mid)) +
              __popcll(__ballot(b4 < mid)) + __popcll(__ballot(b5 < mid));
      bool ge = (c >= 32);
      bhi = ge ? mid : bhi;
      blo = ge ? blo : mid;
    }
    unsigned short v32 = (unsigned short)(bhi - 1u);
    d2k = (float)__builtin_bit_cast(__fp16, v32);

    float d32 = sqrtf(d2k) + 1e-2f;
    float mxl = (cxl > 0) ? xg.x - (-4.5f + cxl * CW) : 1e9f;
    float mxh = (cxh < GRIDC - 1) ? (-4.5f + (cxh + 1) * CW) - xg.x : 1e9f;
    float myl = (cyl > 0) ? xg.y - (-4.5f + cyl * CW) : 1e9f;
    float myh = (cyh < GRIDC - 1) ? (-4.5f + (cyh + 1) * CW) - xg.y : 1e9f;
    float margin = fminf(fminf(mxl, mxh), fminf(myl, myh));
    if (d32 <= margin) break;
    int nr = (3 * r + 1) >> 1;
    if (nr > 11) fullA = true; else r = nr;
  }

  const float den = fmaf(2.0f, d2k, 1e-8f);
  const float nc1 = -1.4426950408889634f / den;  // w_scaled = 2^(10 + nc1*d)
  const float dcut = 9.704f * den;               // cut at scaled weight 2^-4

  // phase B: weight sums (banded or full contiguous), LDS reads
  float sw = 0.f, swx = 0.f, swy = 0.f;
  {
    const int bxl = cellc(xg.x - dcut), bxh = cellc(xg.x + dcut);
    const int byl = cellc(xg.y - dcut), byh = cellc(xg.y + dcut);
    const bool fullB = (byh - byl + 1 > 20);
#define WACC(qp)                                                     \
    {                                                                \
      u32 e = pksub(xihu, qp);                                       \
      float d = __builtin_amdgcn_sqrtf(dot2u(e, e, 0.0f));           \
      float wgt = __builtin_amdgcn_exp2f(fmaf(nc1, d, 10.0f));       \
      h2 ph = __builtin_bit_cast(h2, qp);                            \
      sw += wgt;                                                     \
      swx = fmaf(wgt, (float)ph.x, swx);                             \
      swy = fmaf(wgt, (float)ph.y, swy);                             \
    }
    if (fullB) {
      for (u32 j = (u32)s; j < N_PTS; j += 64u) { u32 qp = sptL[j]; WACC(qp); }
    } else {
      u32 acc = 0;
      for (int yy = byl; yy <= byh; ++yy) {
        const int rowb = yy << 6;
        u32 lo = base[rowb + bxl];
        u32 len = base[rowb + bxh + 1] - lo;
        u32 k0 = ((u32)s - acc) & 63u;
        for (u32 k = k0; k < len; k += 64u) { u32 qp = sptL[lo + k]; WACC(qp); }
        acc += len;
      }
    }
#undef WACC
  }
#pragma unroll
  for (int m = 1; m < 64; m <<= 1) {
    sw  += __shfl_xor(sw,  m);
    swx += __shfl_xor(swx, m);
    swy += __shfl_xor(swy, m);
  }

  if (s < 2) {
    const float mean = stats[s];
    float inv   = 1.0f / (sw + 1e-8f);               // 2^10 scaling cancels in drift
    float drift = (s == 0 ? swx : swy) * inv - mean;
    float xcv   = (s == 0 ? xg.x : xg.y) - mean;
    uint32_t idx = 2u * (uint32_t)orig + (uint32_t)s;
    hbuf[idx] = fmaf(0.5f, drift - xcv, xcv) + jax_noise(idx);
  }
}

// ======= K3: every block reduces hbuf (deterministic) + writes scaled slice =======
__global__ __launch_bounds__(256) void scalefinal_kernel(const float* __restrict__ stats,
                                                         const float* __restrict__ hbuf,
                                                         float* __restrict__ out) {
  __shared__ double red[256][4];
  __shared__ float sc[2];
  const int t = threadIdx.x;
  double s0 = 0, s1 = 0, q0 = 0, q1 = 0;
#pragma unroll
  for (int k = 0; k < 32; ++k) {
    float2 v = ((const float2*)hbuf)[t + k * 256];
    s0 += (double)v.x; s1 += (double)v.y;
    q0 += (double)v.x * (double)v.x; q1 += (double)v.y * (double)v.y;
  }
  red[t][0] = s0; red[t][1] = s1; red[t][2] = q0; red[t][3] = q1;
  __syncthreads();
  for (int st = 128; st > 0; st >>= 1) {
    if (t < st) {
      red[t][0] += red[t + st][0]; red[t][1] += red[t + st][1];
      red[t][2] += red[t + st][2]; red[t][3] += red[t + st][3];
    }
    __syncthreads();
  }
  if (t < 2) {
    double n = (double)N_PTS;
    double m = red[0][t] / n;
    double v = (red[0][2 + t] - n * m * m) / (n - 1.0);
    sc[t] = stats[2 + t] / ((float)sqrt(v) + 1e-8f);
  }
  __syncthreads();
  int i = blockIdx.x * 256 + t;
  int d = i & 1;
  out[i] = fmaf(hbuf[i], sc[d], stats[d]);
}

extern "C" void kernel_launch(void* const* d_in, const int* in_sizes, int n_in,
                              void* d_out, int out_size, void* d_ws, size_t ws_size,
                              hipStream_t stream) {
  const float* x = (const float*)d_in[0];
  float* out = (float*)d_out;
  char* W = (char*)d_ws;
  float* stats = (float*)W;                               // 16 B
  u32* base   = (u32*)(W + 128);                          // 4097 u32
  u32* iimg   = (u32*)(W + 16640);                        // 65*65 u32
  unsigned short* sidx = (unsigned short*)(W + 33664);    // 8192 u16
  u32* tmp_pt = (u32*)(W + 50048);                        // 8192 u32
  u32* tmp_ci = (u32*)(W + 82816);                        // 8192 u32
  u32* spt    = (u32*)(W + 115584);                       // 8192 u32; ends 148352
  float* hbuf = (float*)(W + 50048);                      // overlays tmp (dead after build)

  build_kernel<<<1, 1024, 0, stream>>>(x, stats, base, iimg, tmp_pt, tmp_ci, spt, sidx);
  main_kernel<<<NBLK, TPB, 0, stream>>>(x, stats, base, iimg, spt, sidx, hbuf);
  scalefinal_kernel<<<16384 / 256, 256, 0, stream>>>(stats, hbuf, out);
}

// Round 12
// 65.458 us; speedup vs baseline: 1.3003x; 1.3003x over previous
//
#include <hip/hip_runtime.h>
#include <stdint.h>
#include <math.h>

#define N_PTS 8192
#define WPB   8
#define TPB   (WPB * 64)           // 512
#define NBLK  (N_PTS / WPB)        // 1024 blocks for main
#define GRIDC 64
#define NCELL (GRIDC * GRIDC)
#define CW    (9.0f / 64.0f)
#define CINV  (64.0f / 9.0f)

typedef __fp16 h2 __attribute__((ext_vector_type(2)));
typedef uint32_t u32;

__device__ __forceinline__ u32 pksub(u32 a, u32 b) {
  u32 d;
  asm("v_pk_add_f16 %0, %1, %2 neg_lo:[0,1] neg_hi:[0,1]" : "=v"(d) : "v"(a), "v"(b));
  return d;
}
__device__ __forceinline__ float dot2u(u32 a, u32 b, float c) {
#if __has_builtin(__builtin_amdgcn_fdot2)
  return __builtin_amdgcn_fdot2(__builtin_bit_cast(h2, a), __builtin_bit_cast(h2, b), c, false);
#else
  h2 x = __builtin_bit_cast(h2, a), y = __builtin_bit_cast(h2, b);
  return fmaf((float)x.x, (float)y.x, fmaf((float)x.y, (float)y.y, c));
#endif
}
__device__ __forceinline__ u32 cvtpk(float a, float b) {
  return __builtin_bit_cast(u32, __builtin_amdgcn_cvt_pkrtz(a, b));
}
__device__ __forceinline__ int cellc(float v) {
  int c = (int)floorf((v + 4.5f) * CINV);
  return c < 0 ? 0 : (c > GRIDC - 1 ? GRIDC - 1 : c);
}

// ---------------- threefry2x32 (JAX partitionable random_bits) ----------------
__device__ __forceinline__ uint32_t rotl32(uint32_t x, int r) {
  return (x << r) | (x >> (32 - r));
}
__device__ __forceinline__ uint32_t threefry_bits(uint32_t idx) {
  const uint32_t k0 = 0u, k1 = 42u;
  const uint32_t k2c = k0 ^ k1 ^ 0x1BD11BDAu;
  uint32_t x0 = 0u, x1 = idx;
  x0 += k0; x1 += k1;
  x0 += x1; x1 = rotl32(x1, 13); x1 ^= x0;
  x0 += x1; x1 = rotl32(x1, 15); x1 ^= x0;
  x0 += x1; x1 = rotl32(x1, 26); x1 ^= x0;
  x0 += x1; x1 = rotl32(x1,  6); x1 ^= x0;
  x0 += k1; x1 += k2c + 1u;
  x0 += x1; x1 = rotl32(x1, 17); x1 ^= x0;
  x0 += x1; x1 = rotl32(x1, 29); x1 ^= x0;
  x0 += x1; x1 = rotl32(x1, 16); x1 ^= x0;
  x0 += x1; x1 = rotl32(x1, 24); x1 ^= x0;
  x0 += k2c; x1 += k0 + 2u;
  x0 += x1; x1 = rotl32(x1, 13); x1 ^= x0;
  x0 += x1; x1 = rotl32(x1, 15); x1 ^= x0;
  x0 += x1; x1 = rotl32(x1, 26); x1 ^= x0;
  x0 += x1; x1 = rotl32(x1,  6); x1 ^= x0;
  x0 += k0; x1 += k1 + 3u;
  x0 += x1; x1 = rotl32(x1, 17); x1 ^= x0;
  x0 += x1; x1 = rotl32(x1, 29); x1 ^= x0;
  x0 += x1; x1 = rotl32(x1, 16); x1 ^= x0;
  x0 += x1; x1 = rotl32(x1, 24); x1 ^= x0;
  x0 += k1; x1 += k2c + 4u;
  x0 += x1; x1 = rotl32(x1, 13); x1 ^= x0;
  x0 += x1; x1 = rotl32(x1, 15); x1 ^= x0;
  x0 += x1; x1 = rotl32(x1, 26); x1 ^= x0;
  x0 += x1; x1 = rotl32(x1,  6); x1 ^= x0;
  x0 += k2c; x1 += k0 + 5u;
  return x0 ^ x1;
}
__device__ __forceinline__ float erfinv_xla(float x) {
  float w = -log1pf(-x * x);
  float p;
  if (w < 5.0f) {
    w -= 2.5f;
    p = 2.81022636e-08f;
    p = fmaf(p, w, 3.43273939e-07f);
    p = fmaf(p, w, -3.5233877e-06f);
    p = fmaf(p, w, -4.39150654e-06f);
    p = fmaf(p, w, 0.00021858087f);
    p = fmaf(p, w, -0.00125372503f);
    p = fmaf(p, w, -0.00417768164f);
    p = fmaf(p, w, 0.246640727f);
    p = fmaf(p, w, 1.50140941f);
  } else {
    w = sqrtf(w) - 3.0f;
    p = -0.000200214257f;
    p = fmaf(p, w, 0.000100950558f);
    p = fmaf(p, w, 0.00134934322f);
    p = fmaf(p, w, -0.00367342844f);
    p = fmaf(p, w, 0.00573950773f);
    p = fmaf(p, w, -0.0076224613f);
    p = fmaf(p, w, 0.00943887047f);
    p = fmaf(p, w, 1.00167406f);
    p = fmaf(p, w, 2.83297682f);
  }
  return p * x;
}
__device__ __forceinline__ float jax_noise(uint32_t idx) {
  uint32_t bits = threefry_bits(idx);
  float uf = __uint_as_float((bits >> 9) | 0x3F800000u) - 1.0f;
  const float lo_u = -0.99999994f;
  float u = fmaxf(lo_u, fmaf(uf, 2.0f, lo_u));
  return 1.4142135623730951f * erfinv_xla(u) * 0.01f;
}

// ======= K1: single-block LDS-only build: hist + prefix + iimg + stats + cursor =======
__global__ __launch_bounds__(1024) void build1_kernel(const float* __restrict__ x,
                                                      float* __restrict__ stats,
                                                      u32* __restrict__ base,
                                                      u32* __restrict__ cursor,
                                                      u32* __restrict__ iimg) {
  __shared__ u32 baseL[NCELL];
  __shared__ u32 ssc[1024];
  __shared__ double sred[16][4];
  const int t = threadIdx.x;

#pragma unroll
  for (int k = 0; k < 4; ++k) baseL[t * 4 + k] = 0;
  __syncthreads();

  // histogram (LDS atomics) + f64 stat partials
  double s0 = 0, s1 = 0, q0 = 0, q1 = 0;
#pragma unroll
  for (int k = 0; k < 8; ++k) {
    float2 p = ((const float2*)x)[t * 8 + k];
    int cell = cellc(p.y) * GRIDC + cellc(p.x);
    atomicAdd(&baseL[cell], 1u);
    s0 += (double)p.x; s1 += (double)p.y;
    q0 += (double)p.x * (double)p.x; q1 += (double)p.y * (double)p.y;
  }
#pragma unroll
  for (int m = 1; m < 64; m <<= 1) {
    s0 += __shfl_xor(s0, m); s1 += __shfl_xor(s1, m);
    q0 += __shfl_xor(q0, m); q1 += __shfl_xor(q1, m);
  }
  if ((t & 63) == 0) {
    sred[t >> 6][0] = s0; sred[t >> 6][1] = s1;
    sred[t >> 6][2] = q0; sred[t >> 6][3] = q1;
  }
  __syncthreads();

  // prefix sum over 4096 cells (4 per thread)
  u32 c0 = baseL[t * 4], c1 = baseL[t * 4 + 1], c2 = baseL[t * 4 + 2], c3 = baseL[t * 4 + 3];
  u32 sum = c0 + c1 + c2 + c3;
  ssc[t] = sum;
  __syncthreads();
  for (int off = 1; off < 1024; off <<= 1) {
    u32 v = (t >= off) ? ssc[t - off] : 0u;
    __syncthreads();
    ssc[t] += v;
    __syncthreads();
  }
  u32 run = ssc[t] - sum;  // exclusive
  u32 b0 = run, b1 = run + c0, b2 = b1 + c1, b3 = b2 + c2;
  __syncthreads();
  baseL[t * 4] = b0; baseL[t * 4 + 1] = b1; baseL[t * 4 + 2] = b2; baseL[t * 4 + 3] = b3;
  base[t * 4] = b0;   base[t * 4 + 1] = b1;   base[t * 4 + 2] = b2;   base[t * 4 + 3] = b3;
  cursor[t * 4] = b0; cursor[t * 4 + 1] = b1; cursor[t * 4 + 2] = b2; cursor[t * 4 + 3] = b3;
  if (t == 1023) base[NCELL] = N_PTS;
  if (t == 0) {
    double a0 = 0, a1 = 0, d0 = 0, d1 = 0;
    for (int k = 0; k < 16; ++k) {
      a0 += sred[k][0]; a1 += sred[k][1]; d0 += sred[k][2]; d1 += sred[k][3];
    }
    double n = (double)N_PTS, m0 = a0 / n, m1 = a1 / n;
    stats[0] = (float)m0; stats[1] = (float)m1;
    stats[2] = (float)sqrt((d0 - n * m0 * m0) / (n - 1.0));
    stats[3] = (float)sqrt((d1 - n * m1 * m1) / (n - 1.0));
  }
  __syncthreads();

  // integral image from exclusive base: row-band partial counts
  if (t <= 64) {
    u32 acc = 0;
    iimg[t] = 0;
    for (int yy = 0; yy < GRIDC; ++yy) {
      int idx = yy * GRIDC + t;
      u32 v = (idx < NCELL) ? baseL[idx] : (u32)N_PTS;
      acc += v - baseL[yy * GRIDC];
      iimg[(yy + 1) * 65 + t] = acc;
    }
  }
}

// ======= K2: place (parallel global scatter) =======
__global__ __launch_bounds__(256) void place_kernel(const float* __restrict__ x,
                                                    u32* __restrict__ cursor,
                                                    u32* __restrict__ tmp_pt,
                                                    u32* __restrict__ tmp_ci) {
  int i = blockIdx.x * 256 + threadIdx.x;
  float2 p = ((const float2*)x)[i];
  int cell = cellc(p.y) * GRIDC + cellc(p.x);
  u32 slot = atomicAdd(&cursor[cell], 1u);
  tmp_pt[slot] = cvtpk(p.x, p.y);
  tmp_ci[slot] = ((u32)cell << 13) | (u32)i;
}

// ======= K3: stable rank within cell (parallel global gather) =======
__global__ __launch_bounds__(256) void rank_kernel(const u32* __restrict__ base,
                                                   const u32* __restrict__ tmp_pt,
                                                   const u32* __restrict__ tmp_ci,
                                                   u32* __restrict__ spt,
                                                   unsigned short* __restrict__ sidx) {
  int s = blockIdx.x * 256 + threadIdx.x;
  u32 v = tmp_ci[s];
  u32 cell = v >> 13, i = v & 8191u;
  u32 lo = base[cell], hi = base[cell + 1];
  u32 rank = 0;
  for (u32 j = lo; j < hi; ++j) rank += ((tmp_ci[j] & 8191u) < i) ? 1u : 0u;
  u32 d = lo + rank;
  spt[d] = tmp_pt[s];
  sidx[d] = (unsigned short)i;
}

// ======= K4: main — LDS-resident point set, windowed sigma + drift + noised h =======
__global__ __launch_bounds__(TPB, 4) void main_kernel(const float* __restrict__ x,
                                                      const float* __restrict__ stats,
                                                      const u32* __restrict__ base,
                                                      const u32* __restrict__ iimg,
                                                      const u32* __restrict__ spt,
                                                      const unsigned short* __restrict__ sidx,
                                                      float* __restrict__ hbuf) {
  __shared__ u32 sptL[N_PTS];  // 32 KB
  const int t = threadIdx.x;
  const int w = t >> 6;
  const int s = t & 63;

#pragma unroll
  for (int k = 0; k < 4; ++k)
    ((uint4*)sptL)[k * TPB + t] = ((const uint4*)spt)[k * TPB + t];
  __syncthreads();

  const int p = blockIdx.x * WPB + w;
  const int orig = (int)sidx[p];
  const float2 xg = ((const float2*)x)[orig];
  const u32 xihu = cvtpk(xg.x, xg.y);
  const int cx = cellc(xg.x), cy = cellc(xg.y);
  const float INF = 3.402823466e+38f;

  // pre-size r from integral image
  int r = 1;
  bool fullA = false;
  for (;;) {
    int cxl = max(cx - r, 0), cxh = min(cx + r, GRIDC - 1);
    int cyl = max(cy - r, 0), cyh = min(cy + r, GRIDC - 1);
    u32 cnt = iimg[(cyh + 1) * 65 + cxh + 1] - iimg[cyl * 65 + cxh + 1]
            - iimg[(cyh + 1) * 65 + cxl] + iimg[cyl * 65 + cxl];
    if (cnt >= 160u) break;
    int nr = (3 * r + 1) >> 1;
    if (nr > 11) { fullA = true; break; }
    r = nr;
  }

  // phase A: scan + exact rank-32 + verify
  float d2k;
  for (;;) {
    float r0 = INF, r1 = INF, r2 = INF, r3 = INF, r4 = INF, r5 = INF;
    int cxl, cxh, cyl, cyh;
    if (fullA) { cxl = 0; cxh = GRIDC - 1; cyl = 0; cyh = GRIDC - 1; }
    else {
      cxl = max(cx - r, 0); cxh = min(cx + r, GRIDC - 1);
      cyl = max(cy - r, 0); cyh = min(cy + r, GRIDC - 1);
    }
#define INS6(d2)                      \
    r5 = fminf(fmaxf(r4, d2), r5);    \
    r4 = fminf(fmaxf(r3, d2), r4);    \
    r3 = fminf(fmaxf(r2, d2), r3);    \
    r2 = fminf(fmaxf(r1, d2), r2);    \
    r1 = fminf(fmaxf(r0, d2), r1);    \
    r0 = fminf(r0, d2);
    if (fullA) {
      for (u32 j = (u32)s; j < N_PTS; j += 64u) {
        u32 qp = sptL[j];
        u32 e = pksub(xihu, qp);
        float d2 = dot2u(e, e, 0.0f);
        INS6(d2);
      }
    } else {
      u32 acc = 0;  // continuous stream striding across bands
      for (int yy = cyl; yy <= cyh; ++yy) {
        const int rowb = yy << 6;
        u32 lo = base[rowb + cxl];
        u32 len = base[rowb + cxh + 1] - lo;
        u32 k0 = ((u32)s - acc) & 63u;
        for (u32 k = k0; k < len; k += 64u) {
          u32 qp = sptL[lo + k];
          u32 e = pksub(xihu, qp);
          float d2 = dot2u(e, e, 0.0f);
          INS6(d2);
        }
        acc += len;
      }
    }
#undef INS6
    u32 b0 = (u32)__builtin_bit_cast(unsigned short, (__fp16)r0);
    u32 b1 = (u32)__builtin_bit_cast(unsigned short, (__fp16)r1);
    u32 b2 = (u32)__builtin_bit_cast(unsigned short, (__fp16)r2);
    u32 b3 = (u32)__builtin_bit_cast(unsigned short, (__fp16)r3);
    u32 b4 = (u32)__builtin_bit_cast(unsigned short, (__fp16)r4);
    u32 b5 = (u32)__builtin_bit_cast(unsigned short, (__fp16)r5);
    u32 blo = 0u, bhi = 0x7C01u;
    for (int it = 0; it < 15; ++it) {
      u32 mid = (blo + bhi) >> 1;
      int c = __popcll(__ballot(b0 < mid)) + __popcll(__ballot(b1 < mid)) +
              __popcll(__ballot(b2 < mid)) + __popcll(__ballot(b3 < mid)) +
              __popcll(__ballot(b4 < mid)) + __popcll(__ballot(b5 < mid));
      bool ge = (c >= 32);
      bhi = ge ? mid : bhi;
      blo = ge ? blo : mid;
    }
    unsigned short v32 = (unsigned short)(bhi - 1u);
    d2k = (float)__builtin_bit_cast(__fp16, v32);

    float d32 = sqrtf(d2k) + 1e-2f;
    float mxl = (cxl > 0) ? xg.x - (-4.5f + cxl * CW) : 1e9f;
    float mxh = (cxh < GRIDC - 1) ? (-4.5f + (cxh + 1) * CW) - xg.x : 1e9f;
    float myl = (cyl > 0) ? xg.y - (-4.5f + cyl * CW) : 1e9f;
    float myh = (cyh < GRIDC - 1) ? (-4.5f + (cyh + 1) * CW) - xg.y : 1e9f;
    float margin = fminf(fminf(mxl, mxh), fminf(myl, myh));
    if (d32 <= margin) break;
    int nr = (3 * r + 1) >> 1;
    if (nr > 11) fullA = true; else r = nr;
  }

  const float den = fmaf(2.0f, d2k, 1e-8f);
  const float nc1 = -1.4426950408889634f / den;  // w_scaled = 2^(10 + nc1*d)
  const float dcut = 9.704f * den;               // cut at scaled weight 2^-4

  // phase B: weight sums, LDS reads
  float sw = 0.f, swx = 0.f, swy = 0.f;
  {
    const int bxl = cellc(xg.x - dcut), bxh = cellc(xg.x + dcut);
    const int byl = cellc(xg.y - dcut), byh = cellc(xg.y + dcut);
    const bool fullB = (byh - byl + 1 > 20);
#define WACC(qp)                                                     \
    {                                                                \
      u32 e = pksub(xihu, qp);                                       \
      float d = __builtin_amdgcn_sqrtf(dot2u(e, e, 0.0f));           \
      float wgt = __builtin_amdgcn_exp2f(fmaf(nc1, d, 10.0f));       \
      h2 ph = __builtin_bit_cast(h2, qp);                            \
      sw += wgt;                                                     \
      swx = fmaf(wgt, (float)ph.x, swx);                             \
      swy = fmaf(wgt, (float)ph.y, swy);                             \
    }
    if (fullB) {
      for (u32 j = (u32)s; j < N_PTS; j += 64u) { u32 qp = sptL[j]; WACC(qp); }
    } else {
      u32 acc = 0;
      for (int yy = byl; yy <= byh; ++yy) {
        const int rowb = yy << 6;
        u32 lo = base[rowb + bxl];
        u32 len = base[rowb + bxh + 1] - lo;
        u32 k0 = ((u32)s - acc) & 63u;
        for (u32 k = k0; k < len; k += 64u) { u32 qp = sptL[lo + k]; WACC(qp); }
        acc += len;
      }
    }
#undef WACC
  }
#pragma unroll
  for (int m = 1; m < 64; m <<= 1) {
    sw  += __shfl_xor(sw,  m);
    swx += __shfl_xor(swx, m);
    swy += __shfl_xor(swy, m);
  }

  if (s < 2) {
    const float mean = stats[s];
    float inv   = 1.0f / (sw + 1e-8f);               // 2^10 scaling cancels in drift
    float drift = (s == 0 ? swx : swy) * inv - mean;
    float xcv   = (s == 0 ? xg.x : xg.y) - mean;
    uint32_t idx = 2u * (uint32_t)orig + (uint32_t)s;
    hbuf[idx] = fmaf(0.5f, drift - xcv, xcv) + jax_noise(idx);
  }
}

// ======= K5: every block reduces hbuf (deterministic) + writes scaled slice =======
__global__ __launch_bounds__(256) void scalefinal_kernel(const float* __restrict__ stats,
                                                         const float* __restrict__ hbuf,
                                                         float* __restrict__ out) {
  __shared__ double red[256][4];
  __shared__ float sc[2];
  const int t = threadIdx.x;
  double s0 = 0, s1 = 0, q0 = 0, q1 = 0;
#pragma unroll
  for (int k = 0; k < 32; ++k) {
    float2 v = ((const float2*)hbuf)[t + k * 256];
    s0 += (double)v.x; s1 += (double)v.y;
    q0 += (double)v.x * (double)v.x; q1 += (double)v.y * (double)v.y;
  }
  red[t][0] = s0; red[t][1] = s1; red[t][2] = q0; red[t][3] = q1;
  __syncthreads();
  for (int st = 128; st > 0; st >>= 1) {
    if (t < st) {
      red[t][0] += red[t + st][0]; red[t][1] += red[t + st][1];
      red[t][2] += red[t + st][2]; red[t][3] += red[t + st][3];
    }
    __syncthreads();
  }
  if (t < 2) {
    double n = (double)N_PTS;
    double m = red[0][t] / n;
    double v = (red[0][2 + t] - n * m * m) / (n - 1.0);
    sc[t] = stats[2 + t] / ((float)sqrt(v) + 1e-8f);
  }
  __syncthreads();
  int i = blockIdx.x * 256 + t;
  int d = i & 1;
  out[i] = fmaf(hbuf[i], sc[d], stats[d]);
}

extern "C" void kernel_launch(void* const* d_in, const int* in_sizes, int n_in,
                              void* d_out, int out_size, void* d_ws, size_t ws_size,
                              hipStream_t stream) {
  const float* x = (const float*)d_in[0];
  float* out = (float*)d_out;
  char* W = (char*)d_ws;
  float* stats = (float*)W;                               // 16 B
  u32* base   = (u32*)(W + 128);                          // 4097 u32
  u32* cursor = (u32*)(W + 16640);                        // 4096 u32
  u32* iimg   = (u32*)(W + 33152);                        // 65*65 u32
  unsigned short* sidx = (unsigned short*)(W + 50176);    // 8192 u16
  u32* tmp_pt = (u32*)(W + 66560);                        // 8192 u32
  u32* tmp_ci = (u32*)(W + 99328);                        // 8192 u32
  u32* spt    = (u32*)(W + 132096);                       // 8192 u32; ends 164864
  float* hbuf = (float*)(W + 66560);                      // overlays tmp (dead after rank)

  build1_kernel<<<1, 1024, 0, stream>>>(x, stats, base, cursor, iimg);
  place_kernel<<<N_PTS / 256, 256, 0, stream>>>(x, cursor, tmp_pt, tmp_ci);
  rank_kernel<<<N_PTS / 256, 256, 0, stream>>>(base, tmp_pt, tmp_ci, spt, sidx);
  main_kernel<<<NBLK, TPB, 0, stream>>>(x, stats, base, iimg, spt, sidx, hbuf);
  scalefinal_kernel<<<16384 / 256, 256, 0, stream>>>(stats, hbuf, out);
}

// Round 13
// 63.759 us; speedup vs baseline: 1.3349x; 1.0267x over previous
//
#include <hip/hip_runtime.h>
#include <stdint.h>
#include <math.h>

#define N_PTS 8192
#define WPB   16
#define TPB   (WPB * 64)           // 1024
#define NBLK  (N_PTS / WPB)        // 512 blocks for main (1 round at 2 blocks/CU)
#define GRIDC 64
#define NCELL (GRIDC * GRIDC)
#define CW    (9.0f / 64.0f)
#define CINV  (64.0f / 9.0f)

typedef __fp16 h2 __attribute__((ext_vector_type(2)));
typedef uint32_t u32;

__device__ __forceinline__ u32 pksub(u32 a, u32 b) {
  u32 d;
  asm("v_pk_add_f16 %0, %1, %2 neg_lo:[0,1] neg_hi:[0,1]" : "=v"(d) : "v"(a), "v"(b));
  return d;
}
__device__ __forceinline__ float dot2u(u32 a, u32 b, float c) {
#if __has_builtin(__builtin_amdgcn_fdot2)
  return __builtin_amdgcn_fdot2(__builtin_bit_cast(h2, a), __builtin_bit_cast(h2, b), c, false);
#else
  h2 x = __builtin_bit_cast(h2, a), y = __builtin_bit_cast(h2, b);
  return fmaf((float)x.x, (float)y.x, fmaf((float)x.y, (float)y.y, c));
#endif
}
__device__ __forceinline__ u32 cvtpk(float a, float b) {
  return __builtin_bit_cast(u32, __builtin_amdgcn_cvt_pkrtz(a, b));
}
__device__ __forceinline__ int cellc(float v) {
  int c = (int)floorf((v + 4.5f) * CINV);
  return c < 0 ? 0 : (c > GRIDC - 1 ? GRIDC - 1 : c);
}

// ---------------- threefry2x32 (JAX partitionable random_bits) ----------------
__device__ __forceinline__ uint32_t rotl32(uint32_t x, int r) {
  return (x << r) | (x >> (32 - r));
}
__device__ __forceinline__ uint32_t threefry_bits(uint32_t idx) {
  const uint32_t k0 = 0u, k1 = 42u;
  const uint32_t k2c = k0 ^ k1 ^ 0x1BD11BDAu;
  uint32_t x0 = 0u, x1 = idx;
  x0 += k0; x1 += k1;
  x0 += x1; x1 = rotl32(x1, 13); x1 ^= x0;
  x0 += x1; x1 = rotl32(x1, 15); x1 ^= x0;
  x0 += x1; x1 = rotl32(x1, 26); x1 ^= x0;
  x0 += x1; x1 = rotl32(x1,  6); x1 ^= x0;
  x0 += k1; x1 += k2c + 1u;
  x0 += x1; x1 = rotl32(x1, 17); x1 ^= x0;
  x0 += x1; x1 = rotl32(x1, 29); x1 ^= x0;
  x0 += x1; x1 = rotl32(x1, 16); x1 ^= x0;
  x0 += x1; x1 = rotl32(x1, 24); x1 ^= x0;
  x0 += k2c; x1 += k0 + 2u;
  x0 += x1; x1 = rotl32(x1, 13); x1 ^= x0;
  x0 += x1; x1 = rotl32(x1, 15); x1 ^= x0;
  x0 += x1; x1 = rotl32(x1, 26); x1 ^= x0;
  x0 += x1; x1 = rotl32(x1,  6); x1 ^= x0;
  x0 += k0; x1 += k1 + 3u;
  x0 += x1; x1 = rotl32(x1, 17); x1 ^= x0;
  x0 += x1; x1 = rotl32(x1, 29); x1 ^= x0;
  x0 += x1; x1 = rotl32(x1, 16); x1 ^= x0;
  x0 += x1; x1 = rotl32(x1, 24); x1 ^= x0;
  x0 += k1; x1 += k2c + 4u;
  x0 += x1; x1 = rotl32(x1, 13); x1 ^= x0;
  x0 += x1; x1 = rotl32(x1, 15); x1 ^= x0;
  x0 += x1; x1 = rotl32(x1, 26); x1 ^= x0;
  x0 += x1; x1 = rotl32(x1,  6); x1 ^= x0;
  x0 += k2c; x1 += k0 + 5u;
  return x0 ^ x1;
}
__device__ __forceinline__ float erfinv_xla(float x) {
  float w = -log1pf(-x * x);
  float p;
  if (w < 5.0f) {
    w -= 2.5f;
    p = 2.81022636e-08f;
    p = fmaf(p, w, 3.43273939e-07f);
    p = fmaf(p, w, -3.5233877e-06f);
    p = fmaf(p, w, -4.39150654e-06f);
    p = fmaf(p, w, 0.00021858087f);
    p = fmaf(p, w, -0.00125372503f);
    p = fmaf(p, w, -0.00417768164f);
    p = fmaf(p, w, 0.246640727f);
    p = fmaf(p, w, 1.50140941f);
  } else {
    w = sqrtf(w) - 3.0f;
    p = -0.000200214257f;
    p = fmaf(p, w, 0.000100950558f);
    p = fmaf(p, w, 0.00134934322f);
    p = fmaf(p, w, -0.00367342844f);
    p = fmaf(p, w, 0.00573950773f);
    p = fmaf(p, w, -0.0076224613f);
    p = fmaf(p, w, 0.00943887047f);
    p = fmaf(p, w, 1.00167406f);
    p = fmaf(p, w, 2.83297682f);
  }
  return p * x;
}
__device__ __forceinline__ float jax_noise(uint32_t idx) {
  uint32_t bits = threefry_bits(idx);
  float uf = __uint_as_float((bits >> 9) | 0x3F800000u) - 1.0f;
  const float lo_u = -0.99999994f;
  float u = fmaxf(lo_u, fmaf(uf, 2.0f, lo_u));
  return 1.4142135623730951f * erfinv_xla(u) * 0.01f;
}

// ======= K1: single-block LDS-only build: hist + prefix + iimg + stats + cursor =======
__global__ __launch_bounds__(1024) void build1_kernel(const float* __restrict__ x,
                                                      float* __restrict__ stats,
                                                      u32* __restrict__ base,
                                                      u32* __restrict__ cursor,
                                                      u32* __restrict__ iimg) {
  __shared__ u32 baseL[NCELL];
  __shared__ u32 ssc[1024];
  __shared__ double sred[16][4];
  const int t = threadIdx.x;

#pragma unroll
  for (int k = 0; k < 4; ++k) baseL[t * 4 + k] = 0;
  __syncthreads();

  double s0 = 0, s1 = 0, q0 = 0, q1 = 0;
#pragma unroll
  for (int k = 0; k < 8; ++k) {
    float2 p = ((const float2*)x)[t * 8 + k];
    int cell = cellc(p.y) * GRIDC + cellc(p.x);
    atomicAdd(&baseL[cell], 1u);
    s0 += (double)p.x; s1 += (double)p.y;
    q0 += (double)p.x * (double)p.x; q1 += (double)p.y * (double)p.y;
  }
#pragma unroll
  for (int m = 1; m < 64; m <<= 1) {
    s0 += __shfl_xor(s0, m); s1 += __shfl_xor(s1, m);
    q0 += __shfl_xor(q0, m); q1 += __shfl_xor(q1, m);
  }
  if ((t & 63) == 0) {
    sred[t >> 6][0] = s0; sred[t >> 6][1] = s1;
    sred[t >> 6][2] = q0; sred[t >> 6][3] = q1;
  }
  __syncthreads();

  u32 c0 = baseL[t * 4], c1 = baseL[t * 4 + 1], c2 = baseL[t * 4 + 2], c3 = baseL[t * 4 + 3];
  u32 sum = c0 + c1 + c2 + c3;
  ssc[t] = sum;
  __syncthreads();
  for (int off = 1; off < 1024; off <<= 1) {
    u32 v = (t >= off) ? ssc[t - off] : 0u;
    __syncthreads();
    ssc[t] += v;
    __syncthreads();
  }
  u32 run = ssc[t] - sum;  // exclusive
  u32 b0 = run, b1 = run + c0, b2 = b1 + c1, b3 = b2 + c2;
  __syncthreads();
  baseL[t * 4] = b0; baseL[t * 4 + 1] = b1; baseL[t * 4 + 2] = b2; baseL[t * 4 + 3] = b3;
  base[t * 4] = b0;   base[t * 4 + 1] = b1;   base[t * 4 + 2] = b2;   base[t * 4 + 3] = b3;
  cursor[t * 4] = b0; cursor[t * 4 + 1] = b1; cursor[t * 4 + 2] = b2; cursor[t * 4 + 3] = b3;
  if (t == 1023) base[NCELL] = N_PTS;
  if (t == 0) {
    double a0 = 0, a1 = 0, d0 = 0, d1 = 0;
    for (int k = 0; k < 16; ++k) {
      a0 += sred[k][0]; a1 += sred[k][1]; d0 += sred[k][2]; d1 += sred[k][3];
    }
    double n = (double)N_PTS, m0 = a0 / n, m1 = a1 / n;
    stats[0] = (float)m0; stats[1] = (float)m1;
    stats[2] = (float)sqrt((d0 - n * m0 * m0) / (n - 1.0));
    stats[3] = (float)sqrt((d1 - n * m1 * m1) / (n - 1.0));
  }
  __syncthreads();

  if (t <= 64) {
    u32 acc = 0;
    iimg[t] = 0;
    for (int yy = 0; yy < GRIDC; ++yy) {
      int idx = yy * GRIDC + t;
      u32 v = (idx < NCELL) ? baseL[idx] : (u32)N_PTS;
      acc += v - baseL[yy * GRIDC];
      iimg[(yy + 1) * 65 + t] = acc;
    }
  }
}

// ======= K2: place (parallel global scatter) =======
__global__ __launch_bounds__(256) void place_kernel(const float* __restrict__ x,
                                                    u32* __restrict__ cursor,
                                                    u32* __restrict__ tmp_pt,
                                                    u32* __restrict__ tmp_ci) {
  int i = blockIdx.x * 256 + threadIdx.x;
  float2 p = ((const float2*)x)[i];
  int cell = cellc(p.y) * GRIDC + cellc(p.x);
  u32 slot = atomicAdd(&cursor[cell], 1u);
  tmp_pt[slot] = cvtpk(p.x, p.y);
  tmp_ci[slot] = ((u32)cell << 13) | (u32)i;
}

// ======= K3: stable rank within cell (parallel global gather) =======
__global__ __launch_bounds__(256) void rank_kernel(const u32* __restrict__ base,
                                                   const u32* __restrict__ tmp_pt,
                                                   const u32* __restrict__ tmp_ci,
                                                   u32* __restrict__ spt,
                                                   unsigned short* __restrict__ sidx) {
  int s = blockIdx.x * 256 + threadIdx.x;
  u32 v = tmp_ci[s];
  u32 cell = v >> 13, i = v & 8191u;
  u32 lo = base[cell], hi = base[cell + 1];
  u32 rank = 0;
  for (u32 j = lo; j < hi; ++j) rank += ((tmp_ci[j] & 8191u) < i) ? 1u : 0u;
  u32 d = lo + rank;
  spt[d] = tmp_pt[s];
  sidx[d] = (unsigned short)i;
}

// ======= K4: main — LDS-resident points, vectorized/unrolled scans =======
__global__ __launch_bounds__(TPB, 2) void main_kernel(const float* __restrict__ x,
                                                      const float* __restrict__ stats,
                                                      const u32* __restrict__ base,
                                                      const u32* __restrict__ iimg,
                                                      const u32* __restrict__ spt,
                                                      const unsigned short* __restrict__ sidx,
                                                      float* __restrict__ hbuf) {
  __shared__ u32 sptL[N_PTS];  // 32 KB
  const int t = threadIdx.x;
  const int w = t >> 6;
  const int s = t & 63;

#pragma unroll
  for (int k = 0; k < 2; ++k)
    ((uint4*)sptL)[k * TPB + t] = ((const uint4*)spt)[k * TPB + t];
  __syncthreads();

  const int p = blockIdx.x * WPB + w;
  const int orig = (int)sidx[p];
  const float2 xg = ((const float2*)x)[orig];
  const u32 xihu = cvtpk(xg.x, xg.y);
  const int cx = cellc(xg.x), cy = cellc(xg.y);
  const float INF = 3.402823466e+38f;
  const uint4* v4 = (const uint4*)sptL;

  // pre-size r from integral image
  int r = 1;
  bool fullA = false;
  for (;;) {
    int cxl = max(cx - r, 0), cxh = min(cx + r, GRIDC - 1);
    int cyl = max(cy - r, 0), cyh = min(cy + r, GRIDC - 1);
    u32 cnt = iimg[(cyh + 1) * 65 + cxh + 1] - iimg[cyl * 65 + cxh + 1]
            - iimg[(cyh + 1) * 65 + cxl] + iimg[cyl * 65 + cxl];
    if (cnt >= 160u) break;
    int nr = (3 * r + 1) >> 1;
    if (nr > 11) { fullA = true; break; }
    r = nr;
  }

  // phase A: scan + exact rank-32 + verify
  float d2k;
  for (;;) {
    float r0 = INF, r1 = INF, r2 = INF, r3 = INF, r4 = INF, r5 = INF;
    int cxl, cxh, cyl, cyh;
    if (fullA) { cxl = 0; cxh = GRIDC - 1; cyl = 0; cyh = GRIDC - 1; }
    else {
      cxl = max(cx - r, 0); cxh = min(cx + r, GRIDC - 1);
      cyl = max(cy - r, 0); cyh = min(cy + r, GRIDC - 1);
    }
#define INS6(d2)                      \
    r5 = fminf(fmaxf(r4, d2), r5);    \
    r4 = fminf(fmaxf(r3, d2), r4);    \
    r3 = fminf(fmaxf(r2, d2), r3);    \
    r2 = fminf(fmaxf(r1, d2), r2);    \
    r1 = fminf(fmaxf(r0, d2), r1);    \
    r0 = fminf(r0, d2);
#define DQ(qp, dd) { u32 e = pksub(xihu, qp); dd = dot2u(e, e, 0.0f); }
    if (fullA) {
      // vectorized full scan: 16 iters x 2 independent uint4 loads (8 pts/iter)
      for (u32 it = 0; it < 16; ++it) {
        uint4 a = v4[it * 128 + (u32)s];
        uint4 b = v4[it * 128 + 64 + (u32)s];
        float d0, d1, d2, d3, d4, d5, d6, d7;
        DQ(a.x, d0) DQ(a.y, d1) DQ(a.z, d2) DQ(a.w, d3)
        DQ(b.x, d4) DQ(b.y, d5) DQ(b.z, d6) DQ(b.w, d7)
        INS6(d0) INS6(d1) INS6(d2) INS6(d3)
        INS6(d4) INS6(d5) INS6(d6) INS6(d7)
      }
    } else {
      u32 acc = 0;  // continuous stream striding across bands
      for (int yy = cyl; yy <= cyh; ++yy) {
        const int rowb = yy << 6;
        u32 lo = base[rowb + cxl];
        u32 len = base[rowb + cxh + 1] - lo;
        u32 k = ((u32)s - acc) & 63u;
        for (; k + 64u < len; k += 128u) {  // 2 independent loads
          u32 qa = sptL[lo + k];
          u32 qb = sptL[lo + k + 64u];
          float da, db;
          DQ(qa, da) DQ(qb, db)
          INS6(da) INS6(db)
        }
        if (k < len) {
          u32 qa = sptL[lo + k];
          float da;
          DQ(qa, da)
          INS6(da)
        }
        acc += len;
      }
    }
#undef DQ
#undef INS6
    u32 b0 = (u32)__builtin_bit_cast(unsigned short, (__fp16)r0);
    u32 b1 = (u32)__builtin_bit_cast(unsigned short, (__fp16)r1);
    u32 b2 = (u32)__builtin_bit_cast(unsigned short, (__fp16)r2);
    u32 b3 = (u32)__builtin_bit_cast(unsigned short, (__fp16)r3);
    u32 b4 = (u32)__builtin_bit_cast(unsigned short, (__fp16)r4);
    u32 b5 = (u32)__builtin_bit_cast(unsigned short, (__fp16)r5);
    u32 blo = 0u, bhi = 0x7C01u;
    for (int it = 0; it < 15; ++it) {
      u32 mid = (blo + bhi) >> 1;
      int c = __popcll(__ballot(b0 < mid)) + __popcll(__ballot(b1 < mid)) +
              __popcll(__ballot(b2 < mid)) + __popcll(__ballot(b3 < mid)) +
              __popcll(__ballot(b4 < mid)) + __popcll(__ballot(b5 < mid));
      bool ge = (c >= 32);
      bhi = ge ? mid : bhi;
      blo = ge ? blo : mid;
    }
    unsigned short v32 = (unsigned short)(bhi - 1u);
    d2k = (float)__builtin_bit_cast(__fp16, v32);

    float d32 = sqrtf(d2k) + 1e-2f;
    float mxl = (cxl > 0) ? xg.x - (-4.5f + cxl * CW) : 1e9f;
    float mxh = (cxh < GRIDC - 1) ? (-4.5f + (cxh + 1) * CW) - xg.x : 1e9f;
    float myl = (cyl > 0) ? xg.y - (-4.5f + cyl * CW) : 1e9f;
    float myh = (cyh < GRIDC - 1) ? (-4.5f + (cyh + 1) * CW) - xg.y : 1e9f;
    float margin = fminf(fminf(mxl, mxh), fminf(myl, myh));
    if (d32 <= margin) break;
    int nr = (3 * r + 1) >> 1;
    if (nr > 11) fullA = true; else r = nr;
  }

  const float den = fmaf(2.0f, d2k, 1e-8f);
  const float nc1 = -1.4426950408889634f / den;  // w_scaled = 2^(10 + nc1*d)
  const float dcut = 9.704f * den;               // cut at scaled weight 2^-4

  // phase B: weight sums, LDS reads (vectorized full or unrolled banded)
  float sw = 0.f, swx = 0.f, swy = 0.f;
  {
    const int bxl = cellc(xg.x - dcut), bxh = cellc(xg.x + dcut);
    const int byl = cellc(xg.y - dcut), byh = cellc(xg.y + dcut);
    const bool fullB = (byh - byl + 1 > 20);
#define WACC(qp)                                                     \
    {                                                                \
      u32 e = pksub(xihu, qp);                                       \
      float d = __builtin_amdgcn_sqrtf(dot2u(e, e, 0.0f));           \
      float wgt = __builtin_amdgcn_exp2f(fmaf(nc1, d, 10.0f));       \
      h2 ph = __builtin_bit_cast(h2, qp);                            \
      sw += wgt;                                                     \
      swx = fmaf(wgt, (float)ph.x, swx);                             \
      swy = fmaf(wgt, (float)ph.y, swy);                             \
    }
    if (fullB) {
      for (u32 it = 0; it < 16; ++it) {
        uint4 a = v4[it * 128 + (u32)s];
        uint4 b = v4[it * 128 + 64 + (u32)s];
        WACC(a.x) WACC(a.y) WACC(a.z) WACC(a.w)
        WACC(b.x) WACC(b.y) WACC(b.z) WACC(b.w)
      }
    } else {
      u32 acc = 0;
      for (int yy = byl; yy <= byh; ++yy) {
        const int rowb = yy << 6;
        u32 lo = base[rowb + bxl];
        u32 len = base[rowb + bxh + 1] - lo;
        u32 k = ((u32)s - acc) & 63u;
        for (; k + 64u < len; k += 128u) {
          u32 qa = sptL[lo + k];
          u32 qb = sptL[lo + k + 64u];
          WACC(qa) WACC(qb)
        }
        if (k < len) { u32 qa = sptL[lo + k]; WACC(qa) }
        acc += len;
      }
    }
#undef WACC
  }
#pragma unroll
  for (int m = 1; m < 64; m <<= 1) {
    sw  += __shfl_xor(sw,  m);
    swx += __shfl_xor(swx, m);
    swy += __shfl_xor(swy, m);
  }

  if (s < 2) {
    const float mean = stats[s];
    float inv   = 1.0f / (sw + 1e-8f);               // 2^10 scaling cancels in drift
    float drift = (s == 0 ? swx : swy) * inv - mean;
    float xcv   = (s == 0 ? xg.x : xg.y) - mean;
    uint32_t idx = 2u * (uint32_t)orig + (uint32_t)s;
    hbuf[idx] = fmaf(0.5f, drift - xcv, xcv) + jax_noise(idx);
  }
}

// ======= K5: every block reduces hbuf (deterministic) + writes scaled slice =======
__global__ __launch_bounds__(256) void scalefinal_kernel(const float* __restrict__ stats,
                                                         const float* __restrict__ hbuf,
                                                         float* __restrict__ out) {
  __shared__ double red[256][4];
  __shared__ float sc[2];
  const int t = threadIdx.x;
  double s0 = 0, s1 = 0, q0 = 0, q1 = 0;
#pragma unroll
  for (int k = 0; k < 32; ++k) {
    float2 v = ((const float2*)hbuf)[t + k * 256];
    s0 += (double)v.x; s1 += (double)v.y;
    q0 += (double)v.x * (double)v.x; q1 += (double)v.y * (double)v.y;
  }
  red[t][0] = s0; red[t][1] = s1; red[t][2] = q0; red[t][3] = q1;
  __syncthreads();
  for (int st = 128; st > 0; st >>= 1) {
    if (t < st) {
      red[t][0] += red[t + st][0]; red[t][1] += red[t + st][1];
      red[t][2] += red[t + st][2]; red[t][3] += red[t + st][3];
    }
    __syncthreads();
  }
  if (t < 2) {
    double n = (double)N_PTS;
    double m = red[0][t] / n;
    double v = (red[0][2 + t] - n * m * m) / (n - 1.0);
    sc[t] = stats[2 + t] / ((float)sqrt(v) + 1e-8f);
  }
  __syncthreads();
  int i = blockIdx.x * 256 + t;
  int d = i & 1;
  out[i] = fmaf(hbuf[i], sc[d], stats[d]);
}

extern "C" void kernel_launch(void* const* d_in, const int* in_sizes, int n_in,
                              void* d_out, int out_size, void* d_ws, size_t ws_size,
                              hipStream_t stream) {
  const float* x = (const float*)d_in[0];
  float* out = (float*)d_out;
  char* W = (char*)d_ws;
  float* stats = (float*)W;                               // 16 B
  u32* base   = (u32*)(W + 128);                          // 4097 u32
  u32* cursor = (u32*)(W + 16640);                        // 4096 u32
  u32* iimg   = (u32*)(W + 33152);                        // 65*65 u32
  unsigned short* sidx = (unsigned short*)(W + 50176);    // 8192 u16
  u32* tmp_pt = (u32*)(W + 66560);                        // 8192 u32
  u32* tmp_ci = (u32*)(W + 99328);                        // 8192 u32
  u32* spt    = (u32*)(W + 132096);                       // 8192 u32; ends 164864
  float* hbuf = (float*)(W + 66560);                      // overlays tmp (dead after rank)

  build1_kernel<<<1, 1024, 0, stream>>>(x, stats, base, cursor, iimg);
  place_kernel<<<N_PTS / 256, 256, 0, stream>>>(x, cursor, tmp_pt, tmp_ci);
  rank_kernel<<<N_PTS / 256, 256, 0, stream>>>(base, tmp_pt, tmp_ci, spt, sidx);
  main_kernel<<<NBLK, TPB, 0, stream>>>(x, stats, base, iimg, spt, sidx, hbuf);
  scalefinal_kernel<<<16384 / 256, 256, 0, stream>>>(stats, hbuf, out);
}

// Round 14
// 53.446 us; speedup vs baseline: 1.5925x; 1.1929x over previous
//
#include <hip/hip_runtime.h>
#include <stdint.h>
#include <math.h>

#define N_PTS 8192
#define WPB   16
#define TPB   (WPB * 64)           // 1024
#define NBLK  (N_PTS / WPB)        // 512 blocks for main (1 round at 2 blocks/CU)
#define GRIDC 64
#define NCELL (GRIDC * GRIDC)
#define CW    (9.0f / 64.0f)
#define CINV  (64.0f / 9.0f)

typedef __fp16 h2 __attribute__((ext_vector_type(2)));
typedef uint32_t u32;

__device__ __forceinline__ u32 pksub(u32 a, u32 b) {
  u32 d;
  asm("v_pk_add_f16 %0, %1, %2 neg_lo:[0,1] neg_hi:[0,1]" : "=v"(d) : "v"(a), "v"(b));
  return d;
}
__device__ __forceinline__ float dot2u(u32 a, u32 b, float c) {
#if __has_builtin(__builtin_amdgcn_fdot2)
  return __builtin_amdgcn_fdot2(__builtin_bit_cast(h2, a), __builtin_bit_cast(h2, b), c, false);
#else
  h2 x = __builtin_bit_cast(h2, a), y = __builtin_bit_cast(h2, b);
  return fmaf((float)x.x, (float)y.x, fmaf((float)x.y, (float)y.y, c));
#endif
}
__device__ __forceinline__ u32 cvtpk(float a, float b) {
  return __builtin_bit_cast(u32, __builtin_amdgcn_cvt_pkrtz(a, b));
}
__device__ __forceinline__ int cellc(float v) {
  int c = (int)floorf((v + 4.5f) * CINV);
  return c < 0 ? 0 : (c > GRIDC - 1 ? GRIDC - 1 : c);
}

// ---------------- threefry2x32 (JAX partitionable random_bits) ----------------
__device__ __forceinline__ uint32_t rotl32(uint32_t x, int r) {
  return (x << r) | (x >> (32 - r));
}
__device__ __forceinline__ uint32_t threefry_bits(uint32_t idx) {
  const uint32_t k0 = 0u, k1 = 42u;
  const uint32_t k2c = k0 ^ k1 ^ 0x1BD11BDAu;
  uint32_t x0 = 0u, x1 = idx;
  x0 += k0; x1 += k1;
  x0 += x1; x1 = rotl32(x1, 13); x1 ^= x0;
  x0 += x1; x1 = rotl32(x1, 15); x1 ^= x0;
  x0 += x1; x1 = rotl32(x1, 26); x1 ^= x0;
  x0 += x1; x1 = rotl32(x1,  6); x1 ^= x0;
  x0 += k1; x1 += k2c + 1u;
  x0 += x1; x1 = rotl32(x1, 17); x1 ^= x0;
  x0 += x1; x1 = rotl32(x1, 29); x1 ^= x0;
  x0 += x1; x1 = rotl32(x1, 16); x1 ^= x0;
  x0 += x1; x1 = rotl32(x1, 24); x1 ^= x0;
  x0 += k2c; x1 += k0 + 2u;
  x0 += x1; x1 = rotl32(x1, 13); x1 ^= x0;
  x0 += x1; x1 = rotl32(x1, 15); x1 ^= x0;
  x0 += x1; x1 = rotl32(x1, 26); x1 ^= x0;
  x0 += x1; x1 = rotl32(x1,  6); x1 ^= x0;
  x0 += k0; x1 += k1 + 3u;
  x0 += x1; x1 = rotl32(x1, 17); x1 ^= x0;
  x0 += x1; x1 = rotl32(x1, 29); x1 ^= x0;
  x0 += x1; x1 = rotl32(x1, 16); x1 ^= x0;
  x0 += x1; x1 = rotl32(x1, 24); x1 ^= x0;
  x0 += k1; x1 += k2c + 4u;
  x0 += x1; x1 = rotl32(x1, 13); x1 ^= x0;
  x0 += x1; x1 = rotl32(x1, 15); x1 ^= x0;
  x0 += x1; x1 = rotl32(x1, 26); x1 ^= x0;
  x0 += x1; x1 = rotl32(x1,  6); x1 ^= x0;
  x0 += k2c; x1 += k0 + 5u;
  return x0 ^ x1;
}
__device__ __forceinline__ float erfinv_xla(float x) {
  float w = -log1pf(-x * x);
  float p;
  if (w < 5.0f) {
    w -= 2.5f;
    p = 2.81022636e-08f;
    p = fmaf(p, w, 3.43273939e-07f);
    p = fmaf(p, w, -3.5233877e-06f);
    p = fmaf(p, w, -4.39150654e-06f);
    p = fmaf(p, w, 0.00021858087f);
    p = fmaf(p, w, -0.00125372503f);
    p = fmaf(p, w, -0.00417768164f);
    p = fmaf(p, w, 0.246640727f);
    p = fmaf(p, w, 1.50140941f);
  } else {
    w = sqrtf(w) - 3.0f;
    p = -0.000200214257f;
    p = fmaf(p, w, 0.000100950558f);
    p = fmaf(p, w, 0.00134934322f);
    p = fmaf(p, w, -0.00367342844f);
    p = fmaf(p, w, 0.00573950773f);
    p = fmaf(p, w, -0.0076224613f);
    p = fmaf(p, w, 0.00943887047f);
    p = fmaf(p, w, 1.00167406f);
    p = fmaf(p, w, 2.83297682f);
  }
  return p * x;
}
__device__ __forceinline__ float jax_noise(uint32_t idx) {
  uint32_t bits = threefry_bits(idx);
  float uf = __uint_as_float((bits >> 9) | 0x3F800000u) - 1.0f;
  const float lo_u = -0.99999994f;
  float u = fmaxf(lo_u, fmaf(uf, 2.0f, lo_u));
  return 1.4142135623730951f * erfinv_xla(u) * 0.01f;
}

// ======= K1: single-block LDS-only build: hist + prefix + iimg + stats + cursor =======
__global__ __launch_bounds__(1024) void build1_kernel(const float* __restrict__ x,
                                                      float* __restrict__ stats,
                                                      u32* __restrict__ base,
                                                      u32* __restrict__ cursor,
                                                      u32* __restrict__ iimg) {
  __shared__ u32 baseL[NCELL];
  __shared__ u32 ssc[1024];
  __shared__ double sred[16][4];
  const int t = threadIdx.x;

#pragma unroll
  for (int k = 0; k < 4; ++k) baseL[t * 4 + k] = 0;
  __syncthreads();

  double s0 = 0, s1 = 0, q0 = 0, q1 = 0;
#pragma unroll
  for (int k = 0; k < 8; ++k) {
    float2 p = ((const float2*)x)[t * 8 + k];
    int cell = cellc(p.y) * GRIDC + cellc(p.x);
    atomicAdd(&baseL[cell], 1u);
    s0 += (double)p.x; s1 += (double)p.y;
    q0 += (double)p.x * (double)p.x; q1 += (double)p.y * (double)p.y;
  }
#pragma unroll
  for (int m = 1; m < 64; m <<= 1) {
    s0 += __shfl_xor(s0, m); s1 += __shfl_xor(s1, m);
    q0 += __shfl_xor(q0, m); q1 += __shfl_xor(q1, m);
  }
  if ((t & 63) == 0) {
    sred[t >> 6][0] = s0; sred[t >> 6][1] = s1;
    sred[t >> 6][2] = q0; sred[t >> 6][3] = q1;
  }
  __syncthreads();

  u32 c0 = baseL[t * 4], c1 = baseL[t * 4 + 1], c2 = baseL[t * 4 + 2], c3 = baseL[t * 4 + 3];
  u32 sum = c0 + c1 + c2 + c3;
  ssc[t] = sum;
  __syncthreads();
  for (int off = 1; off < 1024; off <<= 1) {
    u32 v = (t >= off) ? ssc[t - off] : 0u;
    __syncthreads();
    ssc[t] += v;
    __syncthreads();
  }
  u32 run = ssc[t] - sum;  // exclusive
  u32 b0 = run, b1 = run + c0, b2 = b1 + c1, b3 = b2 + c2;
  __syncthreads();
  baseL[t * 4] = b0; baseL[t * 4 + 1] = b1; baseL[t * 4 + 2] = b2; baseL[t * 4 + 3] = b3;
  base[t * 4] = b0;   base[t * 4 + 1] = b1;   base[t * 4 + 2] = b2;   base[t * 4 + 3] = b3;
  cursor[t * 4] = b0; cursor[t * 4 + 1] = b1; cursor[t * 4 + 2] = b2; cursor[t * 4 + 3] = b3;
  if (t == 1023) base[NCELL] = N_PTS;
  if (t == 0) {
    double a0 = 0, a1 = 0, d0 = 0, d1 = 0;
    for (int k = 0; k < 16; ++k) {
      a0 += sred[k][0]; a1 += sred[k][1]; d0 += sred[k][2]; d1 += sred[k][3];
    }
    double n = (double)N_PTS, m0 = a0 / n, m1 = a1 / n;
    stats[0] = (float)m0; stats[1] = (float)m1;
    stats[2] = (float)sqrt((d0 - n * m0 * m0) / (n - 1.0));
    stats[3] = (float)sqrt((d1 - n * m1 * m1) / (n - 1.0));
  }
  __syncthreads();

  if (t <= 64) {
    u32 acc = 0;
    iimg[t] = 0;
    for (int yy = 0; yy < GRIDC; ++yy) {
      int idx = yy * GRIDC + t;
      u32 v = (idx < NCELL) ? baseL[idx] : (u32)N_PTS;
      acc += v - baseL[yy * GRIDC];
      iimg[(yy + 1) * 65 + t] = acc;
    }
  }
}

// ======= K2: place (parallel global scatter) =======
__global__ __launch_bounds__(256) void place_kernel(const float* __restrict__ x,
                                                    u32* __restrict__ cursor,
                                                    u32* __restrict__ tmp_pt,
                                                    u32* __restrict__ tmp_ci) {
  int i = blockIdx.x * 256 + threadIdx.x;
  float2 p = ((const float2*)x)[i];
  int cell = cellc(p.y) * GRIDC + cellc(p.x);
  u32 slot = atomicAdd(&cursor[cell], 1u);
  tmp_pt[slot] = cvtpk(p.x, p.y);
  tmp_ci[slot] = ((u32)cell << 13) | (u32)i;
}

// ======= K3: stable rank within cell (parallel global gather) =======
__global__ __launch_bounds__(256) void rank_kernel(const u32* __restrict__ base,
                                                   const u32* __restrict__ tmp_pt,
                                                   const u32* __restrict__ tmp_ci,
                                                   u32* __restrict__ spt,
                                                   unsigned short* __restrict__ sidx) {
  int s = blockIdx.x * 256 + threadIdx.x;
  u32 v = tmp_ci[s];
  u32 cell = v >> 13, i = v & 8191u;
  u32 lo = base[cell], hi = base[cell + 1];
  u32 rank = 0;
  for (u32 j = lo; j < hi; ++j) rank += ((tmp_ci[j] & 8191u) < i) ? 1u : 0u;
  u32 d = lo + rank;
  spt[d] = tmp_pt[s];
  sidx[d] = (unsigned short)i;
}

// ======= K4: main — LDS-resident points; STRIDED row->wave mapping =======
__global__ __launch_bounds__(TPB, 2) void main_kernel(const float* __restrict__ x,
                                                      const float* __restrict__ stats,
                                                      const u32* __restrict__ base,
                                                      const u32* __restrict__ iimg,
                                                      const u32* __restrict__ spt,
                                                      const unsigned short* __restrict__ sidx,
                                                      float* __restrict__ hbuf) {
  __shared__ u32 sptL[N_PTS];  // 32 KB
  const int t = threadIdx.x;
  const int w = t >> 6;
  const int s = t & 63;

#pragma unroll
  for (int k = 0; k < 2; ++k)
    ((uint4*)sptL)[k * TPB + t] = ((const uint4*)spt)[k * TPB + t];
  __syncthreads();

  // STRIDED assignment: consecutive sorted positions (spatially clustered,
  // incl. sparse-edge straggler rows) spread across DIFFERENT blocks.
  const int p = w * NBLK + blockIdx.x;
  const int orig = (int)sidx[p];
  const float2 xg = ((const float2*)x)[orig];
  const u32 xihu = cvtpk(xg.x, xg.y);
  const int cx = cellc(xg.x), cy = cellc(xg.y);
  const float INF = 3.402823466e+38f;
  const uint4* v4 = (const uint4*)sptL;

  // pre-size r from integral image
  int r = 1;
  bool fullA = false;
  for (;;) {
    int cxl = max(cx - r, 0), cxh = min(cx + r, GRIDC - 1);
    int cyl = max(cy - r, 0), cyh = min(cy + r, GRIDC - 1);
    u32 cnt = iimg[(cyh + 1) * 65 + cxh + 1] - iimg[cyl * 65 + cxh + 1]
            - iimg[(cyh + 1) * 65 + cxl] + iimg[cyl * 65 + cxl];
    if (cnt >= 160u) break;
    int nr = (3 * r + 1) >> 1;
    if (nr > 11) { fullA = true; break; }
    r = nr;
  }

  // phase A: scan + exact rank-32 + verify
  float d2k;
  for (;;) {
    float r0 = INF, r1 = INF, r2 = INF, r3 = INF, r4 = INF, r5 = INF;
    int cxl, cxh, cyl, cyh;
    if (fullA) { cxl = 0; cxh = GRIDC - 1; cyl = 0; cyh = GRIDC - 1; }
    else {
      cxl = max(cx - r, 0); cxh = min(cx + r, GRIDC - 1);
      cyl = max(cy - r, 0); cyh = min(cy + r, GRIDC - 1);
    }
#define INS6(d2)                      \
    r5 = fminf(fmaxf(r4, d2), r5);    \
    r4 = fminf(fmaxf(r3, d2), r4);    \
    r3 = fminf(fmaxf(r2, d2), r3);    \
    r2 = fminf(fmaxf(r1, d2), r2);    \
    r1 = fminf(fmaxf(r0, d2), r1);    \
    r0 = fminf(r0, d2);
#define DQ(qp, dd) { u32 e = pksub(xihu, qp); dd = dot2u(e, e, 0.0f); }
    if (fullA) {
      for (u32 it = 0; it < 16; ++it) {
        uint4 a = v4[it * 128 + (u32)s];
        uint4 b = v4[it * 128 + 64 + (u32)s];
        float d0, d1, d2, d3, d4, d5, d6, d7;
        DQ(a.x, d0) DQ(a.y, d1) DQ(a.z, d2) DQ(a.w, d3)
        DQ(b.x, d4) DQ(b.y, d5) DQ(b.z, d6) DQ(b.w, d7)
        INS6(d0) INS6(d1) INS6(d2) INS6(d3)
        INS6(d4) INS6(d5) INS6(d6) INS6(d7)
      }
    } else {
      u32 acc = 0;  // continuous stream striding across bands
      for (int yy = cyl; yy <= cyh; ++yy) {
        const int rowb = yy << 6;
        u32 lo = base[rowb + cxl];
        u32 len = base[rowb + cxh + 1] - lo;
        u32 k = ((u32)s - acc) & 63u;
        for (; k + 64u < len; k += 128u) {
          u32 qa = sptL[lo + k];
          u32 qb = sptL[lo + k + 64u];
          float da, db;
          DQ(qa, da) DQ(qb, db)
          INS6(da) INS6(db)
        }
        if (k < len) {
          u32 qa = sptL[lo + k];
          float da;
          DQ(qa, da)
          INS6(da)
        }
        acc += len;
      }
    }
#undef DQ
#undef INS6
    u32 b0 = (u32)__builtin_bit_cast(unsigned short, (__fp16)r0);
    u32 b1 = (u32)__builtin_bit_cast(unsigned short, (__fp16)r1);
    u32 b2 = (u32)__builtin_bit_cast(unsigned short, (__fp16)r2);
    u32 b3 = (u32)__builtin_bit_cast(unsigned short, (__fp16)r3);
    u32 b4 = (u32)__builtin_bit_cast(unsigned short, (__fp16)r4);
    u32 b5 = (u32)__builtin_bit_cast(unsigned short, (__fp16)r5);
    u32 blo = 0u, bhi = 0x7C01u;
    for (int it = 0; it < 15; ++it) {
      u32 mid = (blo + bhi) >> 1;
      int c = __popcll(__ballot(b0 < mid)) + __popcll(__ballot(b1 < mid)) +
              __popcll(__ballot(b2 < mid)) + __popcll(__ballot(b3 < mid)) +
              __popcll(__ballot(b4 < mid)) + __popcll(__ballot(b5 < mid));
      bool ge = (c >= 32);
      bhi = ge ? mid : bhi;
      blo = ge ? blo : mid;
    }
    unsigned short v32 = (unsigned short)(bhi - 1u);
    d2k = (float)__builtin_bit_cast(__fp16, v32);

    float d32 = sqrtf(d2k) + 1e-2f;
    float mxl = (cxl > 0) ? xg.x - (-4.5f + cxl * CW) : 1e9f;
    float mxh = (cxh < GRIDC - 1) ? (-4.5f + (cxh + 1) * CW) - xg.x : 1e9f;
    float myl = (cyl > 0) ? xg.y - (-4.5f + cyl * CW) : 1e9f;
    float myh = (cyh < GRIDC - 1) ? (-4.5f + (cyh + 1) * CW) - xg.y : 1e9f;
    float margin = fminf(fminf(mxl, mxh), fminf(myl, myh));
    if (d32 <= margin) break;
    int nr = (3 * r + 1) >> 1;
    if (nr > 11) fullA = true; else r = nr;
  }

  const float den = fmaf(2.0f, d2k, 1e-8f);
  const float nc1 = -1.4426950408889634f / den;  // w_scaled = 2^(10 + nc1*d)
  const float dcut = 9.704f * den;               // cut at scaled weight 2^-4

  // phase B: weight sums, LDS reads
  float sw = 0.f, swx = 0.f, swy = 0.f;
  {
    const int bxl = cellc(xg.x - dcut), bxh = cellc(xg.x + dcut);
    const int byl = cellc(xg.y - dcut), byh = cellc(xg.y + dcut);
    const bool fullB = (byh - byl + 1 > 20);
#define WACC(qp)                                                     \
    {                                                                \
      u32 e = pksub(xihu, qp);                                       \
      float d = __builtin_amdgcn_sqrtf(dot2u(e, e, 0.0f));           \
      float wgt = __builtin_amdgcn_exp2f(fmaf(nc1, d, 10.0f));       \
      h2 ph = __builtin_bit_cast(h2, qp);                            \
      sw += wgt;                                                     \
      swx = fmaf(wgt, (float)ph.x, swx);                             \
      swy = fmaf(wgt, (float)ph.y, swy);                             \
    }
    if (fullB) {
      for (u32 it = 0; it < 16; ++it) {
        uint4 a = v4[it * 128 + (u32)s];
        uint4 b = v4[it * 128 + 64 + (u32)s];
        WACC(a.x) WACC(a.y) WACC(a.z) WACC(a.w)
        WACC(b.x) WACC(b.y) WACC(b.z) WACC(b.w)
      }
    } else {
      u32 acc = 0;
      for (int yy = byl; yy <= byh; ++yy) {
        const int rowb = yy << 6;
        u32 lo = base[rowb + bxl];
        u32 len = base[rowb + bxh + 1] - lo;
        u32 k = ((u32)s - acc) & 63u;
        for (; k + 64u < len; k += 128u) {
          u32 qa = sptL[lo + k];
          u32 qb = sptL[lo + k + 64u];
          WACC(qa) WACC(qb)
        }
        if (k < len) { u32 qa = sptL[lo + k]; WACC(qa) }
        acc += len;
      }
    }
#undef WACC
  }
#pragma unroll
  for (int m = 1; m < 64; m <<= 1) {
    sw  += __shfl_xor(sw,  m);
    swx += __shfl_xor(swx, m);
    swy += __shfl_xor(swy, m);
  }

  if (s < 2) {
    const float mean = stats[s];
    float inv   = 1.0f / (sw + 1e-8f);               // 2^10 scaling cancels in drift
    float drift = (s == 0 ? swx : swy) * inv - mean;
    float xcv   = (s == 0 ? xg.x : xg.y) - mean;
    uint32_t idx = 2u * (uint32_t)orig + (uint32_t)s;
    hbuf[idx] = fmaf(0.5f, drift - xcv, xcv) + jax_noise(idx);
  }
}

// ======= K5: every block reduces hbuf (deterministic) + writes scaled slice =======
__global__ __launch_bounds__(256) void scalefinal_kernel(const float* __restrict__ stats,
                                                         const float* __restrict__ hbuf,
                                                         float* __restrict__ out) {
  __shared__ double red[256][4];
  __shared__ float sc[2];
  const int t = threadIdx.x;
  double s0 = 0, s1 = 0, q0 = 0, q1 = 0;
#pragma unroll
  for (int k = 0; k < 32; ++k) {
    float2 v = ((const float2*)hbuf)[t + k * 256];
    s0 += (double)v.x; s1 += (double)v.y;
    q0 += (double)v.x * (double)v.x; q1 += (double)v.y * (double)v.y;
  }
  red[t][0] = s0; red[t][1] = s1; red[t][2] = q0; red[t][3] = q1;
  __syncthreads();
  for (int st = 128; st > 0; st >>= 1) {
    if (t < st) {
      red[t][0] += red[t + st][0]; red[t][1] += red[t + st][1];
      red[t][2] += red[t + st][2]; red[t][3] += red[t + st][3];
    }
    __syncthreads();
  }
  if (t < 2) {
    double n = (double)N_PTS;
    double m = red[0][t] / n;
    double v = (red[0][2 + t] - n * m * m) / (n - 1.0);
    sc[t] = stats[2 + t] / ((float)sqrt(v) + 1e-8f);
  }
  __syncthreads();
  int i = blockIdx.x * 256 + t;
  int d = i & 1;
  out[i] = fmaf(hbuf[i], sc[d], stats[d]);
}

extern "C" void kernel_launch(void* const* d_in, const int* in_sizes, int n_in,
                              void* d_out, int out_size, void* d_ws, size_t ws_size,
                              hipStream_t stream) {
  const float* x = (const float*)d_in[0];
  float* out = (float*)d_out;
  char* W = (char*)d_ws;
  float* stats = (float*)W;                               // 16 B
  u32* base   = (u32*)(W + 128);                          // 4097 u32
  u32* cursor = (u32*)(W + 16640);                        // 4096 u32
  u32* iimg   = (u32*)(W + 33152);                        // 65*65 u32
  unsigned short* sidx = (unsigned short*)(W + 50176);    // 8192 u16
  u32* tmp_pt = (u32*)(W + 66560);                        // 8192 u32
  u32* tmp_ci = (u32*)(W + 99328);                        // 8192 u32
  u32* spt    = (u32*)(W + 132096);                       // 8192 u32; ends 164864
  float* hbuf = (float*)(W + 66560);                      // overlays tmp (dead after rank)

  build1_kernel<<<1, 1024, 0, stream>>>(x, stats, base, cursor, iimg);
  place_kernel<<<N_PTS / 256, 256, 0, stream>>>(x, cursor, tmp_pt, tmp_ci);
  rank_kernel<<<N_PTS / 256, 256, 0, stream>>>(base, tmp_pt, tmp_ci, spt, sidx);
  main_kernel<<<NBLK, TPB, 0, stream>>>(x, stats, base, iimg, spt, sidx, hbuf);
  scalefinal_kernel<<<16384 / 256, 256, 0, stream>>>(stats, hbuf, out);
}

// Round 15
// 52.524 us; speedup vs baseline: 1.6205x; 1.0176x over previous
//
#include <hip/hip_runtime.h>
#include <stdint.h>
#include <math.h>

#define N_PTS 8192
#define WPB   16
#define TPB   (WPB * 64)           // 1024
#define NBLK  (N_PTS / WPB)        // 512 blocks for main (1 round at 2 blocks/CU)
#define GRIDC 64
#define NCELL (GRIDC * GRIDC)
#define CW    (9.0f / 64.0f)
#define CINV  (64.0f / 9.0f)

typedef __fp16 h2 __attribute__((ext_vector_type(2)));
typedef uint32_t u32;

__device__ __forceinline__ u32 pksub(u32 a, u32 b) {
  u32 d;
  asm("v_pk_add_f16 %0, %1, %2 neg_lo:[0,1] neg_hi:[0,1]" : "=v"(d) : "v"(a), "v"(b));
  return d;
}
__device__ __forceinline__ float dot2u(u32 a, u32 b, float c) {
#if __has_builtin(__builtin_amdgcn_fdot2)
  return __builtin_amdgcn_fdot2(__builtin_bit_cast(h2, a), __builtin_bit_cast(h2, b), c, false);
#else
  h2 x = __builtin_bit_cast(h2, a), y = __builtin_bit_cast(h2, b);
  return fmaf((float)x.x, (float)y.x, fmaf((float)x.y, (float)y.y, c));
#endif
}
__device__ __forceinline__ u32 cvtpk(float a, float b) {
  return __builtin_bit_cast(u32, __builtin_amdgcn_cvt_pkrtz(a, b));
}
__device__ __forceinline__ int cellc(float v) {
  int c = (int)floorf((v + 4.5f) * CINV);
  return c < 0 ? 0 : (c > GRIDC - 1 ? GRIDC - 1 : c);
}

// ---------------- threefry2x32 (JAX partitionable random_bits) ----------------
__device__ __forceinline__ uint32_t rotl32(uint32_t x, int r) {
  return (x << r) | (x >> (32 - r));
}
__device__ __forceinline__ uint32_t threefry_bits(uint32_t idx) {
  const uint32_t k0 = 0u, k1 = 42u;
  const uint32_t k2c = k0 ^ k1 ^ 0x1BD11BDAu;
  uint32_t x0 = 0u, x1 = idx;
  x0 += k0; x1 += k1;
  x0 += x1; x1 = rotl32(x1, 13); x1 ^= x0;
  x0 += x1; x1 = rotl32(x1, 15); x1 ^= x0;
  x0 += x1; x1 = rotl32(x1, 26); x1 ^= x0;
  x0 += x1; x1 = rotl32(x1,  6); x1 ^= x0;
  x0 += k1; x1 += k2c + 1u;
  x0 += x1; x1 = rotl32(x1, 17); x1 ^= x0;
  x0 += x1; x1 = rotl32(x1, 29); x1 ^= x0;
  x0 += x1; x1 = rotl32(x1, 16); x1 ^= x0;
  x0 += x1; x1 = rotl32(x1, 24); x1 ^= x0;
  x0 += k2c; x1 += k0 + 2u;
  x0 += x1; x1 = rotl32(x1, 13); x1 ^= x0;
  x0 += x1; x1 = rotl32(x1, 15); x1 ^= x0;
  x0 += x1; x1 = rotl32(x1, 26); x1 ^= x0;
  x0 += x1; x1 = rotl32(x1,  6); x1 ^= x0;
  x0 += k0; x1 += k1 + 3u;
  x0 += x1; x1 = rotl32(x1, 17); x1 ^= x0;
  x0 += x1; x1 = rotl32(x1, 29); x1 ^= x0;
  x0 += x1; x1 = rotl32(x1, 16); x1 ^= x0;
  x0 += x1; x1 = rotl32(x1, 24); x1 ^= x0;
  x0 += k1; x1 += k2c + 4u;
  x0 += x1; x1 = rotl32(x1, 13); x1 ^= x0;
  x0 += x1; x1 = rotl32(x1, 15); x1 ^= x0;
  x0 += x1; x1 = rotl32(x1, 26); x1 ^= x0;
  x0 += x1; x1 = rotl32(x1,  6); x1 ^= x0;
  x0 += k2c; x1 += k0 + 5u;
  return x0 ^ x1;
}
__device__ __forceinline__ float erfinv_xla(float x) {
  float w = -log1pf(-x * x);
  float p;
  if (w < 5.0f) {
    w -= 2.5f;
    p = 2.81022636e-08f;
    p = fmaf(p, w, 3.43273939e-07f);
    p = fmaf(p, w, -3.5233877e-06f);
    p = fmaf(p, w, -4.39150654e-06f);
    p = fmaf(p, w, 0.00021858087f);
    p = fmaf(p, w, -0.00125372503f);
    p = fmaf(p, w, -0.00417768164f);
    p = fmaf(p, w, 0.246640727f);
    p = fmaf(p, w, 1.50140941f);
  } else {
    w = sqrtf(w) - 3.0f;
    p = -0.000200214257f;
    p = fmaf(p, w, 0.000100950558f);
    p = fmaf(p, w, 0.00134934322f);
    p = fmaf(p, w, -0.00367342844f);
    p = fmaf(p, w, 0.00573950773f);
    p = fmaf(p, w, -0.0076224613f);
    p = fmaf(p, w, 0.00943887047f);
    p = fmaf(p, w, 1.00167406f);
    p = fmaf(p, w, 2.83297682f);
  }
  return p * x;
}
__device__ __forceinline__ float jax_noise(uint32_t idx) {
  uint32_t bits = threefry_bits(idx);
  float uf = __uint_as_float((bits >> 9) | 0x3F800000u) - 1.0f;
  const float lo_u = -0.99999994f;
  float u = fmaxf(lo_u, fmaf(uf, 2.0f, lo_u));
  return 1.4142135623730951f * erfinv_xla(u) * 0.01f;
}

// ======= K1: single-block LDS-only build: hist + prefix + iimg + stats + cursor =======
__global__ __launch_bounds__(1024) void build1_kernel(const float* __restrict__ x,
                                                      float* __restrict__ stats,
                                                      u32* __restrict__ base,
                                                      u32* __restrict__ cursor,
                                                      u32* __restrict__ iimg) {
  __shared__ u32 baseL[NCELL];
  __shared__ u32 ssc[1024];
  __shared__ double sred[16][4];
  const int t = threadIdx.x;

#pragma unroll
  for (int k = 0; k < 4; ++k) baseL[t * 4 + k] = 0;
  __syncthreads();

  double s0 = 0, s1 = 0, q0 = 0, q1 = 0;
#pragma unroll
  for (int k = 0; k < 8; ++k) {
    float2 p = ((const float2*)x)[t * 8 + k];
    int cell = cellc(p.y) * GRIDC + cellc(p.x);
    atomicAdd(&baseL[cell], 1u);
    s0 += (double)p.x; s1 += (double)p.y;
    q0 += (double)p.x * (double)p.x; q1 += (double)p.y * (double)p.y;
  }
#pragma unroll
  for (int m = 1; m < 64; m <<= 1) {
    s0 += __shfl_xor(s0, m); s1 += __shfl_xor(s1, m);
    q0 += __shfl_xor(q0, m); q1 += __shfl_xor(q1, m);
  }
  if ((t & 63) == 0) {
    sred[t >> 6][0] = s0; sred[t >> 6][1] = s1;
    sred[t >> 6][2] = q0; sred[t >> 6][3] = q1;
  }
  __syncthreads();

  u32 c0 = baseL[t * 4], c1 = baseL[t * 4 + 1], c2 = baseL[t * 4 + 2], c3 = baseL[t * 4 + 3];
  u32 sum = c0 + c1 + c2 + c3;
  ssc[t] = sum;
  __syncthreads();
  for (int off = 1; off < 1024; off <<= 1) {
    u32 v = (t >= off) ? ssc[t - off] : 0u;
    __syncthreads();
    ssc[t] += v;
    __syncthreads();
  }
  u32 run = ssc[t] - sum;  // exclusive
  u32 b0 = run, b1 = run + c0, b2 = b1 + c1, b3 = b2 + c2;
  __syncthreads();
  baseL[t * 4] = b0; baseL[t * 4 + 1] = b1; baseL[t * 4 + 2] = b2; baseL[t * 4 + 3] = b3;
  base[t * 4] = b0;   base[t * 4 + 1] = b1;   base[t * 4 + 2] = b2;   base[t * 4 + 3] = b3;
  cursor[t * 4] = b0; cursor[t * 4 + 1] = b1; cursor[t * 4 + 2] = b2; cursor[t * 4 + 3] = b3;
  if (t == 1023) base[NCELL] = N_PTS;
  if (t == 0) {
    double a0 = 0, a1 = 0, d0 = 0, d1 = 0;
    for (int k = 0; k < 16; ++k) {
      a0 += sred[k][0]; a1 += sred[k][1]; d0 += sred[k][2]; d1 += sred[k][3];
    }
    double n = (double)N_PTS, m0 = a0 / n, m1 = a1 / n;
    stats[0] = (float)m0; stats[1] = (float)m1;
    stats[2] = (float)sqrt((d0 - n * m0 * m0) / (n - 1.0));
    stats[3] = (float)sqrt((d1 - n * m1 * m1) / (n - 1.0));
  }
  __syncthreads();

  if (t <= 64) {
    u32 acc = 0;
    iimg[t] = 0;
    for (int yy = 0; yy < GRIDC; ++yy) {
      int idx = yy * GRIDC + t;
      u32 v = (idx < NCELL) ? baseL[idx] : (u32)N_PTS;
      acc += v - baseL[yy * GRIDC];
      iimg[(yy + 1) * 65 + t] = acc;
    }
  }
}

// ======= K2: place (parallel global scatter) =======
__global__ __launch_bounds__(256) void place_kernel(const float* __restrict__ x,
                                                    u32* __restrict__ cursor,
                                                    u32* __restrict__ tmp_pt,
                                                    u32* __restrict__ tmp_ci) {
  int i = blockIdx.x * 256 + threadIdx.x;
  float2 p = ((const float2*)x)[i];
  int cell = cellc(p.y) * GRIDC + cellc(p.x);
  u32 slot = atomicAdd(&cursor[cell], 1u);
  tmp_pt[slot] = cvtpk(p.x, p.y);
  tmp_ci[slot] = ((u32)cell << 13) | (u32)i;
}

// ======= K3: stable rank within cell (parallel global gather) =======
__global__ __launch_bounds__(256) void rank_kernel(const u32* __restrict__ base,
                                                   const u32* __restrict__ tmp_pt,
                                                   const u32* __restrict__ tmp_ci,
                                                   u32* __restrict__ spt,
                                                   unsigned short* __restrict__ sidx) {
  int s = blockIdx.x * 256 + threadIdx.x;
  u32 v = tmp_ci[s];
  u32 cell = v >> 13, i = v & 8191u;
  u32 lo = base[cell], hi = base[cell + 1];
  u32 rank = 0;
  for (u32 j = lo; j < hi; ++j) rank += ((tmp_ci[j] & 8191u) < i) ? 1u : 0u;
  u32 d = lo + rank;
  spt[d] = tmp_pt[s];
  sidx[d] = (unsigned short)i;
}

// ======= K4: main — points + base + iimg ALL LDS-resident; strided row mapping =======
__global__ __launch_bounds__(TPB, 2) void main_kernel(const float* __restrict__ x,
                                                      const float* __restrict__ stats,
                                                      const u32* __restrict__ base,
                                                      const u32* __restrict__ iimg,
                                                      const u32* __restrict__ spt,
                                                      const unsigned short* __restrict__ sidx,
                                                      float* __restrict__ hbuf) {
  __shared__ u32 sptL[N_PTS];       // 32 KB
  __shared__ u32 baseL[NCELL + 1];  // 16.4 KB  (band bounds: LDS, not global!)
  __shared__ u32 iimgL[65 * 65];    // 16.9 KB
  const int t = threadIdx.x;
  const int w = t >> 6;
  const int s = t & 63;

#pragma unroll
  for (int k = 0; k < 2; ++k)
    ((uint4*)sptL)[k * TPB + t] = ((const uint4*)spt)[k * TPB + t];
#pragma unroll
  for (int k = 0; k < 4; ++k) baseL[k * TPB + t] = base[k * TPB + t];
  if (t == 0) baseL[NCELL] = N_PTS;
#pragma unroll
  for (int k = 0; k < 5; ++k) {
    int i = k * TPB + t;
    if (i < 65 * 65) iimgL[i] = iimg[i];
  }
  __syncthreads();

  // strided assignment: spatially-clustered straggler rows spread across blocks
  const int p = w * NBLK + blockIdx.x;
  const int orig = (int)sidx[p];
  const float2 xg = ((const float2*)x)[orig];
  const u32 xihu = cvtpk(xg.x, xg.y);
  const int cx = cellc(xg.x), cy = cellc(xg.y);
  const float INF = 3.402823466e+38f;
  const uint4* v4 = (const uint4*)sptL;

  // pre-size r from integral image (LDS)
  int r = 1;
  bool fullA = false;
  for (;;) {
    int cxl = max(cx - r, 0), cxh = min(cx + r, GRIDC - 1);
    int cyl = max(cy - r, 0), cyh = min(cy + r, GRIDC - 1);
    u32 cnt = iimgL[(cyh + 1) * 65 + cxh + 1] - iimgL[cyl * 65 + cxh + 1]
            - iimgL[(cyh + 1) * 65 + cxl] + iimgL[cyl * 65 + cxl];
    if (cnt >= 160u) break;
    int nr = (3 * r + 1) >> 1;
    if (nr > 11) { fullA = true; break; }
    r = nr;
  }

  // phase A: scan + exact rank-32 + verify
  float d2k;
  for (;;) {
    float r0 = INF, r1 = INF, r2 = INF, r3 = INF, r4 = INF, r5 = INF;
    int cxl, cxh, cyl, cyh;
    if (fullA) { cxl = 0; cxh = GRIDC - 1; cyl = 0; cyh = GRIDC - 1; }
    else {
      cxl = max(cx - r, 0); cxh = min(cx + r, GRIDC - 1);
      cyl = max(cy - r, 0); cyh = min(cy + r, GRIDC - 1);
    }
#define INS6(d2)                      \
    r5 = fminf(fmaxf(r4, d2), r5);    \
    r4 = fminf(fmaxf(r3, d2), r4);    \
    r3 = fminf(fmaxf(r2, d2), r3);    \
    r2 = fminf(fmaxf(r1, d2), r2);    \
    r1 = fminf(fmaxf(r0, d2), r1);    \
    r0 = fminf(r0, d2);
#define DQ(qp, dd) { u32 e = pksub(xihu, qp); dd = dot2u(e, e, 0.0f); }
    if (fullA) {
      for (u32 it = 0; it < 16; ++it) {
        uint4 a = v4[it * 128 + (u32)s];
        uint4 b = v4[it * 128 + 64 + (u32)s];
        float d0, d1, d2, d3, d4, d5, d6, d7;
        DQ(a.x, d0) DQ(a.y, d1) DQ(a.z, d2) DQ(a.w, d3)
        DQ(b.x, d4) DQ(b.y, d5) DQ(b.z, d6) DQ(b.w, d7)
        INS6(d0) INS6(d1) INS6(d2) INS6(d3)
        INS6(d4) INS6(d5) INS6(d6) INS6(d7)
      }
    } else {
      u32 acc = 0;  // continuous stream striding across bands
      for (int yy = cyl; yy <= cyh; ++yy) {
        const int rowb = yy << 6;
        u32 lo = baseL[rowb + cxl];
        u32 len = baseL[rowb + cxh + 1] - lo;
        u32 k = ((u32)s - acc) & 63u;
        for (; k + 64u < len; k += 128u) {
          u32 qa = sptL[lo + k];
          u32 qb = sptL[lo + k + 64u];
          float da, db;
          DQ(qa, da) DQ(qb, db)
          INS6(da) INS6(db)
        }
        if (k < len) {
          u32 qa = sptL[lo + k];
          float da;
          DQ(qa, da)
          INS6(da)
        }
        acc += len;
      }
    }
#undef DQ
#undef INS6
    u32 b0 = (u32)__builtin_bit_cast(unsigned short, (__fp16)r0);
    u32 b1 = (u32)__builtin_bit_cast(unsigned short, (__fp16)r1);
    u32 b2 = (u32)__builtin_bit_cast(unsigned short, (__fp16)r2);
    u32 b3 = (u32)__builtin_bit_cast(unsigned short, (__fp16)r3);
    u32 b4 = (u32)__builtin_bit_cast(unsigned short, (__fp16)r4);
    u32 b5 = (u32)__builtin_bit_cast(unsigned short, (__fp16)r5);
    u32 blo = 0u, bhi = 0x7C01u;
    for (int it = 0; it < 15; ++it) {
      u32 mid = (blo + bhi) >> 1;
      int c = __popcll(__ballot(b0 < mid)) + __popcll(__ballot(b1 < mid)) +
              __popcll(__ballot(b2 < mid)) + __popcll(__ballot(b3 < mid)) +
              __popcll(__ballot(b4 < mid)) + __popcll(__ballot(b5 < mid));
      bool ge = (c >= 32);
      bhi = ge ? mid : bhi;
      blo = ge ? blo : mid;
    }
    unsigned short v32 = (unsigned short)(bhi - 1u);
    d2k = (float)__builtin_bit_cast(__fp16, v32);

    float d32 = sqrtf(d2k) + 1e-2f;
    float mxl = (cxl > 0) ? xg.x - (-4.5f + cxl * CW) : 1e9f;
    float mxh = (cxh < GRIDC - 1) ? (-4.5f + (cxh + 1) * CW) - xg.x : 1e9f;
    float myl = (cyl > 0) ? xg.y - (-4.5f + cyl * CW) : 1e9f;
    float myh = (cyh < GRIDC - 1) ? (-4.5f + (cyh + 1) * CW) - xg.y : 1e9f;
    float margin = fminf(fminf(mxl, mxh), fminf(myl, myh));
    if (d32 <= margin) break;
    int nr = (3 * r + 1) >> 1;
    if (nr > 11) fullA = true; else r = nr;
  }

  const float den = fmaf(2.0f, d2k, 1e-8f);
  const float nc1 = -1.4426950408889634f / den;  // w_scaled = 2^(10 + nc1*d)
  const float dcut = 9.704f * den;               // cut at scaled weight 2^-4

  // phase B: weight sums (bounds + points all LDS)
  float sw = 0.f, swx = 0.f, swy = 0.f;
  {
    const int bxl = cellc(xg.x - dcut), bxh = cellc(xg.x + dcut);
    const int byl = cellc(xg.y - dcut), byh = cellc(xg.y + dcut);
    const bool fullB = (byh - byl + 1 > 20);
#define WACC(qp)                                                     \
    {                                                                \
      u32 e = pksub(xihu, qp);                                       \
      float d = __builtin_amdgcn_sqrtf(dot2u(e, e, 0.0f));           \
      float wgt = __builtin_amdgcn_exp2f(fmaf(nc1, d, 10.0f));       \
      h2 ph = __builtin_bit_cast(h2, qp);                            \
      sw += wgt;                                                     \
      swx = fmaf(wgt, (float)ph.x, swx);                             \
      swy = fmaf(wgt, (float)ph.y, swy);                             \
    }
    if (fullB) {
      for (u32 it = 0; it < 16; ++it) {
        uint4 a = v4[it * 128 + (u32)s];
        uint4 b = v4[it * 128 + 64 + (u32)s];
        WACC(a.x) WACC(a.y) WACC(a.z) WACC(a.w)
        WACC(b.x) WACC(b.y) WACC(b.z) WACC(b.w)
      }
    } else {
      u32 acc = 0;
      for (int yy = byl; yy <= byh; ++yy) {
        const int rowb = yy << 6;
        u32 lo = baseL[rowb + bxl];
        u32 len = baseL[rowb + bxh + 1] - lo;
        u32 k = ((u32)s - acc) & 63u;
        for (; k + 64u < len; k += 128u) {
          u32 qa = sptL[lo + k];
          u32 qb = sptL[lo + k + 64u];
          WACC(qa) WACC(qb)
        }
        if (k < len) { u32 qa = sptL[lo + k]; WACC(qa) }
        acc += len;
      }
    }
#undef WACC
  }
#pragma unroll
  for (int m = 1; m < 64; m <<= 1) {
    sw  += __shfl_xor(sw,  m);
    swx += __shfl_xor(swx, m);
    swy += __shfl_xor(swy, m);
  }

  if (s < 2) {
    const float mean = stats[s];
    float inv   = 1.0f / (sw + 1e-8f);               // 2^10 scaling cancels in drift
    float drift = (s == 0 ? swx : swy) * inv - mean;
    float xcv   = (s == 0 ? xg.x : xg.y) - mean;
    uint32_t idx = 2u * (uint32_t)orig + (uint32_t)s;
    hbuf[idx] = fmaf(0.5f, drift - xcv, xcv) + jax_noise(idx);
  }
}

// ======= K5: every block reduces hbuf (deterministic) + writes scaled slice =======
__global__ __launch_bounds__(256) void scalefinal_kernel(const float* __restrict__ stats,
                                                         const float* __restrict__ hbuf,
                                                         float* __restrict__ out) {
  __shared__ double red[256][4];
  __shared__ float sc[2];
  const int t = threadIdx.x;
  double s0 = 0, s1 = 0, q0 = 0, q1 = 0;
#pragma unroll
  for (int k = 0; k < 32; ++k) {
    float2 v = ((const float2*)hbuf)[t + k * 256];
    s0 += (double)v.x; s1 += (double)v.y;
    q0 += (double)v.x * (double)v.x; q1 += (double)v.y * (double)v.y;
  }
  red[t][0] = s0; red[t][1] = s1; red[t][2] = q0; red[t][3] = q1;
  __syncthreads();
  for (int st = 128; st > 0; st >>= 1) {
    if (t < st) {
      red[t][0] += red[t + st][0]; red[t][1] += red[t + st][1];
      red[t][2] += red[t + st][2]; red[t][3] += red[t + st][3];
    }
    __syncthreads();
  }
  if (t < 2) {
    double n = (double)N_PTS;
    double m = red[0][t] / n;
    double v = (red[0][2 + t] - n * m * m) / (n - 1.0);
    sc[t] = stats[2 + t] / ((float)sqrt(v) + 1e-8f);
  }
  __syncthreads();
  int i = blockIdx.x * 256 + t;
  int d = i & 1;
  out[i] = fmaf(hbuf[i], sc[d], stats[d]);
}

extern "C" void kernel_launch(void* const* d_in, const int* in_sizes, int n_in,
                              void* d_out, int out_size, void* d_ws, size_t ws_size,
                              hipStream_t stream) {
  const float* x = (const float*)d_in[0];
  float* out = (float*)d_out;
  char* W = (char*)d_ws;
  float* stats = (float*)W;                               // 16 B
  u32* base   = (u32*)(W + 128);                          // 4097 u32
  u32* cursor = (u32*)(W + 16640);                        // 4096 u32
  u32* iimg   = (u32*)(W + 33152);                        // 65*65 u32
  unsigned short* sidx = (unsigned short*)(W + 50176);    // 8192 u16
  u32* tmp_pt = (u32*)(W + 66560);                        // 8192 u32
  u32* tmp_ci = (u32*)(W + 99328);                        // 8192 u32
  u32* spt    = (u32*)(W + 132096);                       // 8192 u32; ends 164864
  float* hbuf = (float*)(W + 66560);                      // overlays tmp (dead after rank)

  build1_kernel<<<1, 1024, 0, stream>>>(x, stats, base, cursor, iimg);
  place_kernel<<<N_PTS / 256, 256, 0, stream>>>(x, cursor, tmp_pt, tmp_ci);
  rank_kernel<<<N_PTS / 256, 256, 0, stream>>>(base, tmp_pt, tmp_ci, spt, sidx);
  main_kernel<<<NBLK, TPB, 0, stream>>>(x, stats, base, iimg, spt, sidx, hbuf);
  scalefinal_kernel<<<16384 / 256, 256, 0, stream>>>(stats, hbuf, out);
}